// Round 10
// baseline (786.846 us; speedup 1.0000x reference)
//
#include <hip/hip_runtime.h>
#include <hip/hip_bf16.h>
#include <math.h>

// Shapes (fixed by the problem)
#define B_  16
#define C_  32
#define T_  62
#define V_  19
#define D_  128
#define HD_ 256
#define H_  8
#define DH_ 16            // D_/H_
#define ROWS 18848        // B*T*V == B*V*T  (= 16*1178)
#define RT_  1178         // ROWS/16 row-tiles
#define BT_ 992           // B*T
#define BV_ 304           // B*V

typedef __attribute__((ext_vector_type(8))) short short8v;   // 8 bf16 (4 VGPRs)
typedef __attribute__((ext_vector_type(4))) float f32x4;

struct alignas(8) bf4 { __hip_bfloat16 x, y, z, w; };

// ---------------------------------------------------------------------------
// pose [B,C,T,V] -> p_bf [B,T,V,C] (bf16; only consumed by bf16 GEMMs)
__global__ void transpose_kernel(const float* __restrict__ pose, __hip_bfloat16* __restrict__ p_bf) {
    int idx = blockIdx.x * 256 + threadIdx.x;
    if (idx >= B_ * T_ * V_ * C_) return;
    int c = idx & 31;
    int rest = idx >> 5;          // b*T*V + t*V + v
    int v = rest % V_;
    int rest2 = rest / V_;
    int t = rest2 % T_;
    int b = rest2 / T_;
    p_bf[idx] = __float2bfloat16(pose[((size_t)((b * C_ + c) * T_ + t)) * V_ + v]);
}

// ---------------------------------------------------------------------------
// Convert all weight matrices to bf16 into one contiguous buffer (one launch).
__global__ void wconv_kernel(
        const float* s0, const float* s1, const float* s2, const float* s3,
        const float* s4, const float* s5, const float* s6, const float* s7,
        const float* s8, const float* s9, const float* s10, const float* s11,
        __hip_bfloat16* __restrict__ dst) {
    int idx = blockIdx.x * 256 + threadIdx.x;
    if (idx >= 585728) return;
    const float* s; int base;
    if      (idx <   4096) { s = s0;  base = 0;      }
    else if (idx <  20480) { s = s1;  base = 4096;   }
    else if (idx < 118784) { s = s2;  base = 20480;  }
    else if (idx < 151552) { s = s3;  base = 118784; }
    else if (idx < 217088) { s = s4;  base = 151552; }
    else if (idx < 282624) { s = s5;  base = 217088; }
    else if (idx < 315392) { s = s6;  base = 282624; }
    else if (idx < 413696) { s = s7;  base = 315392; }
    else if (idx < 446464) { s = s8;  base = 413696; }
    else if (idx < 512000) { s = s9;  base = 446464; }
    else if (idx < 577536) { s = s10; base = 512000; }
    else                   { s = s11; base = 577536; }
    dst[idx] = __float2bfloat16(s[idx - base]);
}

// ---------------------------------------------------------------------------
// MFMA linear: out[r,n] = epi(bias[n] + sum_k A[r,k]*W[n,k]), A/W bf16, acc fp32.
// One wave per 16x16 tile; grid = (RT_, N/64).
// EPI: 0 none, 1 relu, 2 leaky(0.01), 3 add positional encoding (t = row%62, col=oc)
template<int N, int K, int EPI, bool HASBIAS, bool O32, bool O16>
__global__ __launch_bounds__(256) void mfma_linear(
        const __hip_bfloat16* __restrict__ A, const __hip_bfloat16* __restrict__ W,
        const float* __restrict__ bias, float* __restrict__ out32,
        __hip_bfloat16* __restrict__ out16) {
    int wave = threadIdx.x >> 6;
    int lane = threadIdx.x & 63;
    int rt = blockIdx.x;
    int nt = blockIdx.y * 4 + wave;
    int r0 = rt * 16, n0 = nt * 16;
    int rl = lane & 15;
    int kk = (lane >> 4) * 8;
    const short* Ab = (const short*)A + (size_t)(r0 + rl) * K + kk;
    const short* Wb = (const short*)W + (size_t)(n0 + rl) * K + kk;
    f32x4 acc = {0.f, 0.f, 0.f, 0.f};
    #pragma unroll
    for (int kb = 0; kb < K / 32; ++kb) {
        short8v a = *reinterpret_cast<const short8v*>(Ab + kb * 32);
        short8v b = *reinterpret_cast<const short8v*>(Wb + kb * 32);
        acc = __builtin_amdgcn_mfma_f32_16x16x32_bf16(a, b, acc, 0, 0, 0);
    }
    int oc = n0 + rl;
    int or0 = r0 + (lane >> 4) * 4;
    float bv = HASBIAS ? bias[oc] : 0.f;
    float freq = 0.f;
    if (EPI == 3) freq = expf(-(float)(oc & ~1) * (9.210340371976184f / 128.f));
    #pragma unroll
    for (int j = 0; j < 4; ++j) {
        float v = acc[j] + bv;
        if (EPI == 1) v = fmaxf(v, 0.f);
        if (EPI == 2) v = v >= 0.f ? v : 0.01f * v;
        if (EPI == 3) {
            int t = (or0 + j) % T_;
            float ang = (float)t * freq;
            v += (oc & 1) ? cosf(ang) : sinf(ang);
        }
        if (O32) out32[(size_t)(or0 + j) * N + oc] = v;
        if (O16) out16[(size_t)(or0 + j) * N + oc] = __float2bfloat16(v);
    }
}

// ---------------------------------------------------------------------------
// bias2 v2: e = p @ Wemb^T [BT*V, 256]; one thread per (i,j) pair, float4 LDS.
// bias[bt,i,j,g] = scale * sum_hh Wbias[g,hh] * prelu(e[bt,j,hh] - e[bt,i,hh])
// es stride 260 floats (16B-aligned rows); ei reads wave-broadcast (i uniform
// over 19 consecutive lanes); Wbias block-uniform -> scalar loads.
__global__ __launch_bounds__(384) void bias2_kernel(
        const float* __restrict__ e, const float* __restrict__ prelu_a,
        const float* __restrict__ Wbias, float* __restrict__ bias) {
    int bt = blockIdx.x;
    __shared__ float es[V_ * 260];
    int tid = threadIdx.x;
    // stage 19 rows x 64 float4
    for (int idx = tid; idx < V_ * 64; idx += 384) {
        int v = idx >> 6, h4 = idx & 63;
        float4 val = *reinterpret_cast<const float4*>(
            &e[((size_t)(bt * V_ + v)) * HD_ + h4 * 4]);
        *reinterpret_cast<float4*>(&es[v * 260 + h4 * 4]) = val;
    }
    __syncthreads();
    if (tid < V_ * V_) {
        int i = tid / V_, j = tid - i * V_;
        const float a = prelu_a[0];
        const float scale = 0.35355339059327373f;   // 1/sqrt(8)
        const float* ei = es + i * 260;
        const float* ej = es + j * 260;
        float ag[H_] = {0.f, 0.f, 0.f, 0.f, 0.f, 0.f, 0.f, 0.f};
        #pragma unroll 4
        for (int h4 = 0; h4 < 64; ++h4) {
            float4 vj = *reinterpret_cast<const float4*>(ej + h4 * 4);
            float4 vi = *reinterpret_cast<const float4*>(ei + h4 * 4);
            float d0 = vj.x - vi.x, d1 = vj.y - vi.y, d2 = vj.z - vi.z, d3 = vj.w - vi.w;
            float h0 = d0 >= 0.f ? d0 : a * d0;
            float h1 = d1 >= 0.f ? d1 : a * d1;
            float h2 = d2 >= 0.f ? d2 : a * d2;
            float h3 = d3 >= 0.f ? d3 : a * d3;
            const float* wb = Wbias + h4 * 4;
            #pragma unroll
            for (int g = 0; g < H_; ++g) {
                const float* w = wb + g * HD_;
                ag[g] += w[0] * h0 + w[1] * h1 + w[2] * h2 + w[3] * h3;
            }
        }
        float* bout = bias + ((size_t)bt * (V_ * V_) + tid) * H_;
        #pragma unroll
        for (int g = 0; g < H_; ++g) bout[g] = ag[g] * scale;
    }
}

// ---------------------------------------------------------------------------
// Graph attention: per (bt, h). LDS-staged q/k/v, scores 19x19 in LDS. bf16 out.
__global__ __launch_bounds__(384) void attn_graph_kernel(
        const float* __restrict__ qkv, const float* __restrict__ bias,
        __hip_bfloat16* __restrict__ out) {
    int bt = blockIdx.x;
    int h = blockIdx.y;
    __shared__ float q_lds[V_][20];
    __shared__ float k_lds[V_][20];
    __shared__ float v_lds[V_][20];
    __shared__ float sm[V_][20];
    int tid = threadIdx.x;
    for (int idx = tid; idx < V_ * 4 * 3; idx += 384) {
        int mat = idx / (V_ * 4);
        int rem = idx - mat * (V_ * 4);
        int row = rem >> 2, part = rem & 3;
        float4 val = *reinterpret_cast<const float4*>(
            qkv + ((size_t)(bt * V_ + row)) * 384 + mat * 128 + h * DH_ + part * 4);
        float* dst = (mat == 0 ? q_lds[row] : (mat == 1 ? k_lds[row] : v_lds[row])) + part * 4;
        *reinterpret_cast<float4*>(dst) = val;
    }
    __syncthreads();
    if (tid < V_ * V_) {
        int i = tid / V_, j = tid - i * V_;
        float acc = 0.f;
        #pragma unroll
        for (int c = 0; c < 4; ++c) {
            float4 qv = *reinterpret_cast<const float4*>(&q_lds[i][4 * c]);
            float4 kv = *reinterpret_cast<const float4*>(&k_lds[j][4 * c]);
            acc += qv.x * kv.x + qv.y * kv.y + qv.z * kv.z + qv.w * kv.w;
        }
        sm[i][j] = acc * 0.25f + bias[((size_t)(bt * V_ + i) * V_ + j) * H_ + h];
    }
    __syncthreads();
    if (tid < V_) {
        float m = -1e30f;
        for (int j = 0; j < V_; ++j) m = fmaxf(m, sm[tid][j]);
        float sum = 0.f;
        for (int j = 0; j < V_; ++j) { float e = __expf(sm[tid][j] - m); sm[tid][j] = e; sum += e; }
        float inv = 1.f / sum;
        for (int j = 0; j < V_; ++j) sm[tid][j] *= inv;
    }
    __syncthreads();
    if (tid < V_ * DH_) {
        int i = tid / DH_, d = tid - i * DH_;
        float o = 0.f;
        #pragma unroll 4
        for (int j = 0; j < V_; ++j) o += sm[i][j] * v_lds[j][d];
        out[((size_t)(bt * V_ + i)) * D_ + h * DH_ + d] = __float2bfloat16(o);
    }
}

// ---------------------------------------------------------------------------
// Temporal attention: per (b, h). LDS-staged q/k/v; softmax in registers.
// Lane jt owns j = 4*jj + jt (strided): the 4 lanes of a row read CONSECUTIVE
// k rows (stride 20 floats -> disjoint bank spans, conflict-free).
__global__ __launch_bounds__(256) void attn_temporal_kernel(
        const float* __restrict__ qkv, __hip_bfloat16* __restrict__ out) {
    int b = blockIdx.x;
    int h = blockIdx.y;
    __shared__ float q_lds[T_][20];
    __shared__ float k_lds[T_][20];
    __shared__ float v_lds[T_][20];
    __shared__ float sm[T_][68];
    int tid = threadIdx.x;
    for (int idx = tid; idx < T_ * 4 * 3; idx += 256) {
        int mat = idx / (T_ * 4);
        int rem = idx - mat * (T_ * 4);
        int row = rem >> 2, part = rem & 3;
        float4 val = *reinterpret_cast<const float4*>(
            qkv + ((size_t)(b * T_ + row)) * 384 + mat * 128 + h * DH_ + part * 4);
        float* dst = (mat == 0 ? q_lds[row] : (mat == 1 ? k_lds[row] : v_lds[row])) + part * 4;
        *reinterpret_cast<float4*>(dst) = val;
    }
    __syncthreads();
    if (tid < T_ * 4) {
        int i = tid >> 2, jt = tid & 3;
        float qreg[16];
        #pragma unroll
        for (int c = 0; c < 4; ++c) {
            float4 qv = *reinterpret_cast<const float4*>(&q_lds[i][4 * c]);
            qreg[4 * c + 0] = qv.x * 0.25f;
            qreg[4 * c + 1] = qv.y * 0.25f;
            qreg[4 * c + 2] = qv.z * 0.25f;
            qreg[4 * c + 3] = qv.w * 0.25f;
        }
        float s[16];
        #pragma unroll
        for (int jj = 0; jj < 16; ++jj) {
            int j = jj * 4 + jt;
            float acc = -1e30f;
            if (j < T_) {
                acc = 0.f;
                const float* kr = k_lds[j];
                #pragma unroll
                for (int c = 0; c < 4; ++c) {
                    float4 kv = *reinterpret_cast<const float4*>(&kr[4 * c]);
                    acc += qreg[4*c+0] * kv.x + qreg[4*c+1] * kv.y
                         + qreg[4*c+2] * kv.z + qreg[4*c+3] * kv.w;
                }
            }
            s[jj] = acc;
        }
        float m = -1e30f;
        #pragma unroll
        for (int jj = 0; jj < 16; ++jj) m = fmaxf(m, s[jj]);
        m = fmaxf(m, __shfl_xor(m, 1, 64));
        m = fmaxf(m, __shfl_xor(m, 2, 64));
        float sum = 0.f;
        #pragma unroll
        for (int jj = 0; jj < 16; ++jj) {
            int j = jj * 4 + jt;
            float e = (j < T_) ? __expf(s[jj] - m) : 0.f;
            s[jj] = e;
            sum += e;
        }
        sum += __shfl_xor(sum, 1, 64);
        sum += __shfl_xor(sum, 2, 64);
        float inv = 1.f / sum;
        #pragma unroll
        for (int jj = 0; jj < 16; ++jj) {
            int j = jj * 4 + jt;
            if (j < T_) sm[i][j] = s[jj] * inv;
        }
    }
    __syncthreads();
    if (tid < T_ * 4) {
        int i = tid >> 2, dg = tid & 3;
        float4 o = {0.f, 0.f, 0.f, 0.f};
        for (int j = 0; j < T_; ++j) {
            float pp = sm[i][j];
            const float4 vv = *reinterpret_cast<const float4*>(&v_lds[j][4 * dg]);
            o.x += pp * vv.x; o.y += pp * vv.y; o.z += pp * vv.z; o.w += pp * vv.w;
        }
        bf4 ov = { __float2bfloat16(o.x), __float2bfloat16(o.y),
                   __float2bfloat16(o.z), __float2bfloat16(o.w) };
        *reinterpret_cast<bf4*>(out + ((size_t)(b * T_ + i)) * D_ + h * DH_ + 4 * dg) = ov;
    }
}

// ---------------------------------------------------------------------------
// out = LN(x + r) * g + b; optionally fp32 and/or bf16 outputs.
template<bool O32, bool O16>
__global__ __launch_bounds__(64) void ln_add_kernel(
        const float* __restrict__ x, const float* __restrict__ r,
        const float* __restrict__ g, const float* __restrict__ b,
        float* __restrict__ o32, __hip_bfloat16* __restrict__ o16) {
    int row = blockIdx.x;
    int lane = threadIdx.x;
    const float* xr = x + (size_t)row * D_;
    const float* rr = r + (size_t)row * D_;
    float v0 = xr[lane] + rr[lane];
    float v1 = xr[lane + 64] + rr[lane + 64];
    float s = v0 + v1, sq = v0 * v0 + v1 * v1;
    #pragma unroll
    for (int off = 32; off > 0; off >>= 1) {
        s += __shfl_xor(s, off, 64);
        sq += __shfl_xor(sq, off, 64);
    }
    float mean = s * (1.f / 128.f);
    float var = sq * (1.f / 128.f) - mean * mean;
    float rstd = rsqrtf(var + 1e-5f);
    float a0 = (v0 - mean) * rstd * g[lane]      + b[lane];
    float a1 = (v1 - mean) * rstd * g[lane + 64] + b[lane + 64];
    if (O32) {
        float* o = o32 + (size_t)row * D_;
        o[lane] = a0; o[lane + 64] = a1;
    }
    if (O16) {
        __hip_bfloat16* o = o16 + (size_t)row * D_;
        o[lane] = __float2bfloat16(a0); o[lane + 64] = __float2bfloat16(a1);
    }
}

// y += LN(x + r)*g + b; y_bf = bf16(y)   (fused temporal tail)
__global__ __launch_bounds__(64) void ln_add_add_kernel(
        const float* __restrict__ x, const float* __restrict__ r,
        const float* __restrict__ g, const float* __restrict__ b,
        float* __restrict__ y, __hip_bfloat16* __restrict__ y_bf) {
    int row = blockIdx.x;
    int lane = threadIdx.x;
    const float* xr = x + (size_t)row * D_;
    const float* rr = r + (size_t)row * D_;
    float v0 = xr[lane] + rr[lane];
    float v1 = xr[lane + 64] + rr[lane + 64];
    float s = v0 + v1, sq = v0 * v0 + v1 * v1;
    #pragma unroll
    for (int off = 32; off > 0; off >>= 1) {
        s += __shfl_xor(s, off, 64);
        sq += __shfl_xor(sq, off, 64);
    }
    float mean = s * (1.f / 128.f);
    float var = sq * (1.f / 128.f) - mean * mean;
    float rstd = rsqrtf(var + 1e-5f);
    float a0 = (v0 - mean) * rstd * g[lane]      + b[lane];
    float a1 = (v1 - mean) * rstd * g[lane + 64] + b[lane + 64];
    float* yp = y + (size_t)row * D_;
    __hip_bfloat16* yb = y_bf + (size_t)row * D_;
    float y0 = yp[lane] + a0;
    float y1v = yp[lane + 64] + a1;
    yp[lane] = y0;       yb[lane] = __float2bfloat16(y0);
    yp[lane + 64] = y1v; yb[lane + 64] = __float2bfloat16(y1v);
}

// ---------------------------------------------------------------------------
extern "C" void kernel_launch(void* const* d_in, const int* in_sizes, int n_in,
                              void* d_out, int out_size, void* d_ws, size_t ws_size,
                              hipStream_t stream) {
    const float* pose    = (const float*)d_in[0];
    const float* W_pose  = (const float*)d_in[1];
    const float* W_emb   = (const float*)d_in[2];
    const float* prelu_a = (const float*)d_in[3];
    const float* W_bias  = (const float*)d_in[4];
    const float* gWqkv   = (const float*)d_in[5];
    const float* gbqkv   = (const float*)d_in[6];
    const float* gWo     = (const float*)d_in[7];
    const float* gbo     = (const float*)d_in[8];
    const float* gln1g   = (const float*)d_in[9];
    const float* gln1b   = (const float*)d_in[10];
    const float* gW1     = (const float*)d_in[11];
    const float* gb1     = (const float*)d_in[12];
    const float* gW2     = (const float*)d_in[13];
    const float* gb2     = (const float*)d_in[14];
    const float* gln2g   = (const float*)d_in[15];
    const float* gln2b   = (const float*)d_in[16];
    const float* deW     = (const float*)d_in[17];
    const float* deb     = (const float*)d_in[18];
    const float* tWqkv   = (const float*)d_in[19];
    const float* tbqkv   = (const float*)d_in[20];
    const float* tWo     = (const float*)d_in[21];
    const float* tbo     = (const float*)d_in[22];
    const float* tln1g   = (const float*)d_in[23];
    const float* tln1b   = (const float*)d_in[24];
    const float* tW1     = (const float*)d_in[25];
    const float* tb1     = (const float*)d_in[26];
    const float* tW2     = (const float*)d_in[27];
    const float* tb2     = (const float*)d_in[28];
    const float* tln2g   = (const float*)d_in[29];
    const float* tln2b   = (const float*)d_in[30];
    const float* W_out   = (const float*)d_in[31];

    float* ws = (float*)d_ws;
    // workspace layout (float-slot offsets)
    __hip_bfloat16* p_bf   = (__hip_bfloat16*)(ws + 0);          // ROWS*32 bf16
    float*          y      = ws + 301568;                        // ROWS*128 f32
    __hip_bfloat16* y_bf   = (__hip_bfloat16*)(ws + 2714112);    // ROWS*128 bf16
    float*          biasbuf= ws + 3920384;                       // BT*361*8 f32
    float*          big    = ws + 6785280;                       // 7,237,632 f32
    float*          e      = big;                                // ROWS*256 f32 (pre-qkv)
    float*          qkvf   = big;                                // ROWS*384 f32
    float*          tmp    = big;                                // ROWS*128 f32 (post-attn)
    __hip_bfloat16* hid_bf = (__hip_bfloat16*)(big + 2412544);   // ROWS*256 bf16
    float*          y1     = big + 4825088;                      // ROWS*128 f32
    __hip_bfloat16* attn_bf= (__hip_bfloat16*)(ws + 14022912);   // ROWS*128 bf16
    float*          t2     = ws + 15229184;                      // ROWS*128 f32 region
    __hip_bfloat16* y1_bf  = (__hip_bfloat16*)t2;                // (phase-disjoint with t2)
    __hip_bfloat16* t2_bf  = (__hip_bfloat16*)t2;
    __hip_bfloat16* w_bf   = (__hip_bfloat16*)(ws + 17641728);   // 585,728 bf16 weights
    float*          outf   = (float*)d_out;

    // bf16 weight offsets (elems)
    const int oWpose = 0, oWemb = 4096, oGqkv = 20480, oGwo = 118784, oGw1 = 151552,
              oGw2 = 217088, oDe = 282624, oTqkv = 315392, oTwo = 413696,
              oTw1 = 446464, oTw2 = 512000, oWout = 577536;

    wconv_kernel<<<(585728 + 255) / 256, 256, 0, stream>>>(
        W_pose, W_emb, gWqkv, gWo, gW1, gW2, deW, tWqkv, tWo, tW1, tW2, W_out, w_bf);
    transpose_kernel<<<(B_*T_*V_*C_ + 255) / 256, 256, 0, stream>>>(pose, p_bf);
    // y = p @ W_pose^T
    mfma_linear<128, 32, 0, false, true, true><<<dim3(RT_, 2), 256, 0, stream>>>(
        p_bf, w_bf + oWpose, nullptr, y, y_bf);

    for (int i = 0; i < 2; ++i) {
        // ---- graph encoder ----
        mfma_linear<256, 32, 0, false, true, false><<<dim3(RT_, 4), 256, 0, stream>>>(
            p_bf, w_bf + oWemb + i * 8192, nullptr, e, nullptr);
        bias2_kernel<<<BT_, 384, 0, stream>>>(
            e, prelu_a + i, W_bias + (size_t)i * H_ * HD_, biasbuf);
        mfma_linear<384, 128, 0, true, true, false><<<dim3(RT_, 6), 256, 0, stream>>>(
            y_bf, w_bf + oGqkv + i * 49152, gbqkv + (size_t)i * 384, qkvf, nullptr);
        attn_graph_kernel<<<dim3(BT_, H_), 384, 0, stream>>>(qkvf, biasbuf, attn_bf);
        mfma_linear<128, 128, 0, true, true, false><<<dim3(RT_, 2), 256, 0, stream>>>(
            attn_bf, w_bf + oGwo + i * 16384, gbo + (size_t)i * D_, tmp, nullptr);
        ln_add_kernel<true, true><<<ROWS, 64, 0, stream>>>(
            y, tmp, gln1g + (size_t)i * D_, gln1b + (size_t)i * D_, y1, y1_bf);
        mfma_linear<256, 128, 1, true, false, true><<<dim3(RT_, 4), 256, 0, stream>>>(
            y1_bf, w_bf + oGw1 + i * 32768, gb1 + (size_t)i * HD_, nullptr, hid_bf);
        mfma_linear<128, 256, 0, true, true, false><<<dim3(RT_, 2), 256, 0, stream>>>(
            hid_bf, w_bf + oGw2 + i * 32768, gb2 + (size_t)i * D_, tmp, nullptr);
        ln_add_kernel<false, true><<<ROWS, 64, 0, stream>>>(
            y1, tmp, gln2g + (size_t)i * D_, gln2b + (size_t)i * D_, nullptr, t2_bf);
        // y = de@t2 + deb + PE   (fused positional-encoding epilogue)
        mfma_linear<128, 128, 3, true, true, true><<<dim3(RT_, 2), 256, 0, stream>>>(
            t2_bf, w_bf + oDe + i * 16384, deb + (size_t)i * D_, y, y_bf);

        // ---- temporal encoder ----
        mfma_linear<384, 128, 0, true, true, false><<<dim3(RT_, 6), 256, 0, stream>>>(
            y_bf, w_bf + oTqkv + i * 49152, tbqkv + (size_t)i * 384, qkvf, nullptr);
        attn_temporal_kernel<<<dim3(BV_, H_), 256, 0, stream>>>(qkvf, attn_bf);
        mfma_linear<128, 128, 0, true, true, false><<<dim3(RT_, 2), 256, 0, stream>>>(
            attn_bf, w_bf + oTwo + i * 16384, tbo + (size_t)i * D_, tmp, nullptr);
        ln_add_kernel<true, true><<<ROWS, 64, 0, stream>>>(
            y, tmp, tln1g + (size_t)i * D_, tln1b + (size_t)i * D_, y1, y1_bf);
        mfma_linear<256, 128, 1, true, false, true><<<dim3(RT_, 4), 256, 0, stream>>>(
            y1_bf, w_bf + oTw1 + i * 32768, tb1 + (size_t)i * HD_, nullptr, hid_bf);
        mfma_linear<128, 256, 0, true, true, false><<<dim3(RT_, 2), 256, 0, stream>>>(
            hid_bf, w_bf + oTw2 + i * 32768, tb2 + (size_t)i * D_, tmp, nullptr);
        // y += LN(y1 + tmp)  (fused ln_add + add)
        ln_add_add_kernel<<<ROWS, 64, 0, stream>>>(
            y1, tmp, tln2g + (size_t)i * D_, tln2b + (size_t)i * D_, y, y_bf);
    }

    // final projection + LeakyReLU
    mfma_linear<64, 128, 2, false, true, false><<<dim3(RT_, 1), 256, 0, stream>>>(
        y_bf, w_bf + oWout, nullptr, outf, nullptr);
}

// Round 11
// 738.425 us; speedup vs baseline: 1.0656x; 1.0656x over previous
//
#include <hip/hip_runtime.h>
#include <hip/hip_bf16.h>
#include <math.h>

// Shapes (fixed by the problem)
#define B_  16
#define C_  32
#define T_  62
#define V_  19
#define D_  128
#define HD_ 256
#define H_  8
#define DH_ 16            // D_/H_
#define ROWS 18848        // B*T*V == B*V*T  (= 16*1178)
#define RT_  1178         // ROWS/16 row-tiles
#define BT_ 992           // B*T
#define BV_ 304           // B*V

typedef __attribute__((ext_vector_type(8))) short short8v;   // 8 bf16 (4 VGPRs)
typedef __attribute__((ext_vector_type(4))) float f32x4;

struct alignas(8) bf4 { __hip_bfloat16 x, y, z, w; };

// ---------------------------------------------------------------------------
// pose [B,C,T,V] -> p_bf [B,T,V,C] (bf16; only consumed by bf16 GEMMs)
__global__ void transpose_kernel(const float* __restrict__ pose, __hip_bfloat16* __restrict__ p_bf) {
    int idx = blockIdx.x * 256 + threadIdx.x;
    if (idx >= B_ * T_ * V_ * C_) return;
    int c = idx & 31;
    int rest = idx >> 5;          // b*T*V + t*V + v
    int v = rest % V_;
    int rest2 = rest / V_;
    int t = rest2 % T_;
    int b = rest2 / T_;
    p_bf[idx] = __float2bfloat16(pose[((size_t)((b * C_ + c) * T_ + t)) * V_ + v]);
}

// ---------------------------------------------------------------------------
// Convert all weight matrices to bf16 into one contiguous buffer (one launch).
__global__ void wconv_kernel(
        const float* s0, const float* s1, const float* s2, const float* s3,
        const float* s4, const float* s5, const float* s6, const float* s7,
        const float* s8, const float* s9, const float* s10, const float* s11,
        __hip_bfloat16* __restrict__ dst) {
    int idx = blockIdx.x * 256 + threadIdx.x;
    if (idx >= 585728) return;
    const float* s; int base;
    if      (idx <   4096) { s = s0;  base = 0;      }
    else if (idx <  20480) { s = s1;  base = 4096;   }
    else if (idx < 118784) { s = s2;  base = 20480;  }
    else if (idx < 151552) { s = s3;  base = 118784; }
    else if (idx < 217088) { s = s4;  base = 151552; }
    else if (idx < 282624) { s = s5;  base = 217088; }
    else if (idx < 315392) { s = s6;  base = 282624; }
    else if (idx < 413696) { s = s7;  base = 315392; }
    else if (idx < 446464) { s = s8;  base = 413696; }
    else if (idx < 512000) { s = s9;  base = 446464; }
    else if (idx < 577536) { s = s10; base = 512000; }
    else                   { s = s11; base = 577536; }
    dst[idx] = __float2bfloat16(s[idx - base]);
}

// ---------------------------------------------------------------------------
// W2[layer][g][c] = sum_hh Wbias[layer,g,hh] * Wemb[layer,hh,c]   (8x32 per layer)
__global__ __launch_bounds__(512) void w2_kernel(
        const float* __restrict__ Wbias, const float* __restrict__ Wemb,
        float* __restrict__ w2) {
    int tid = threadIdx.x;
    int layer = tid >> 8, g = (tid >> 5) & 7, c = tid & 31;
    float acc = 0.f;
    for (int hh = 0; hh < HD_; ++hh)
        acc += Wbias[layer * 2048 + g * HD_ + hh] * Wemb[layer * 8192 + hh * C_ + c];
    w2[layer * 256 + g * C_ + c] = acc;
}

// ---------------------------------------------------------------------------
// MFMA linear: out[r,n] = epi(bias[n] + sum_k A[r,k]*W[n,k]), A/W bf16, acc fp32.
// One wave per 16x16 tile; grid = (RT_, N/64).
// EPI: 0 none, 1 relu, 2 leaky(0.01), 3 add positional encoding (t = row%62, col=oc)
template<int N, int K, int EPI, bool HASBIAS, bool O32, bool O16>
__global__ __launch_bounds__(256) void mfma_linear(
        const __hip_bfloat16* __restrict__ A, const __hip_bfloat16* __restrict__ W,
        const float* __restrict__ bias, float* __restrict__ out32,
        __hip_bfloat16* __restrict__ out16) {
    int wave = threadIdx.x >> 6;
    int lane = threadIdx.x & 63;
    int rt = blockIdx.x;
    int nt = blockIdx.y * 4 + wave;
    int r0 = rt * 16, n0 = nt * 16;
    int rl = lane & 15;
    int kk = (lane >> 4) * 8;
    const short* Ab = (const short*)A + (size_t)(r0 + rl) * K + kk;
    const short* Wb = (const short*)W + (size_t)(n0 + rl) * K + kk;
    f32x4 acc = {0.f, 0.f, 0.f, 0.f};
    #pragma unroll
    for (int kb = 0; kb < K / 32; ++kb) {
        short8v a = *reinterpret_cast<const short8v*>(Ab + kb * 32);
        short8v b = *reinterpret_cast<const short8v*>(Wb + kb * 32);
        acc = __builtin_amdgcn_mfma_f32_16x16x32_bf16(a, b, acc, 0, 0, 0);
    }
    int oc = n0 + rl;
    int or0 = r0 + (lane >> 4) * 4;
    float bv = HASBIAS ? bias[oc] : 0.f;
    float freq = 0.f;
    if (EPI == 3) freq = expf(-(float)(oc & ~1) * (9.210340371976184f / 128.f));
    #pragma unroll
    for (int j = 0; j < 4; ++j) {
        float v = acc[j] + bv;
        if (EPI == 1) v = fmaxf(v, 0.f);
        if (EPI == 2) v = v >= 0.f ? v : 0.01f * v;
        if (EPI == 3) {
            int t = (or0 + j) % T_;
            float ang = (float)t * freq;
            v += (oc & 1) ? cosf(ang) : sinf(ang);
        }
        if (O32) out32[(size_t)(or0 + j) * N + oc] = v;
        if (O16) out16[(size_t)(or0 + j) * N + oc] = __float2bfloat16(v);
    }
}

// ---------------------------------------------------------------------------
// bias2 v3: prelu(x) = cL'*x + cA'*|x| decomposition.
// linear term telescopes: sum_h W[g,h]*(e_j - e_i)_h = f[j,g] - f[i,g],
//   f[v,g] = p[v,:] @ W2[g,:]  (K=32, W2 = Wbias@Wemb precomputed).
// |d| term is SYMMETRIC in (i,j): only 190 upper-tri pairs (3 waves vs 6).
// es stride 257 (==1 mod 32): scalar reads conflict-free (v1 layout).
__global__ __launch_bounds__(256) void bias2_kernel(
        const float* __restrict__ e, const __hip_bfloat16* __restrict__ p_bf,
        const float* __restrict__ prelu_a, const float* __restrict__ Wbias,
        const float* __restrict__ w2, float* __restrict__ bias) {
    int bt = blockIdx.x;
    __shared__ float es[V_ * 257];
    __shared__ float ps[V_ * 33];
    __shared__ float f_lds[V_ * 8];
    int tid = threadIdx.x;
    // stage e (19x256): float4 global load, scalar LDS stores
    for (int idx = tid; idx < V_ * 64; idx += 256) {
        int v = idx >> 6, h4 = idx & 63;
        float4 val = *reinterpret_cast<const float4*>(
            &e[((size_t)(bt * V_ + v)) * HD_ + h4 * 4]);
        float* d = &es[v * 257 + h4 * 4];
        d[0] = val.x; d[1] = val.y; d[2] = val.z; d[3] = val.w;
    }
    // stage p (19x32 bf16 -> f32)
    if (tid < V_ * 8) {
        int v = tid >> 3, c4 = (tid & 7) * 4;
        bf4 pv = *reinterpret_cast<const bf4*>(&p_bf[((size_t)(bt * V_ + v)) * C_ + c4]);
        float* d = &ps[v * 33 + c4];
        d[0] = __bfloat162float(pv.x); d[1] = __bfloat162float(pv.y);
        d[2] = __bfloat162float(pv.z); d[3] = __bfloat162float(pv.w);
    }
    __syncthreads();
    // phase 1: f[v,g] = ps[v,:] . w2[g,:]  (K=32)
    if (tid < V_ * 8) {
        int v = tid >> 3, g = tid & 7;
        const float* pr = &ps[v * 33];
        const float* wr = &w2[g * C_];
        float acc = 0.f;
        #pragma unroll
        for (int c = 0; c < C_; ++c) acc += pr[c] * wr[c];
        f_lds[v * 8 + g] = acc;
    }
    __syncthreads();
    // phase 2: 190 upper-tri pairs
    if (tid < 190) {
        int i = 0, rem = tid, cnt = V_;
        while (rem >= cnt) { rem -= cnt; ++i; --cnt; }
        int j = i + rem;                       // i <= j
        const float a = prelu_a[0];
        const float scale = 0.35355339059327373f;   // 1/sqrt(8)
        const float cL = 0.5f * (1.f + a) * scale;
        const float cA = 0.5f * (1.f - a) * scale;
        const float* ei = es + i * 257;
        const float* ej = es + j * 257;
        float S[H_] = {0.f, 0.f, 0.f, 0.f, 0.f, 0.f, 0.f, 0.f};
        #pragma unroll 4
        for (int hh = 0; hh < HD_; ++hh) {
            float d = ej[hh] - ei[hh];
            float ad = fabsf(d);
            const float* w = Wbias + hh;       // block-uniform -> s_load
            #pragma unroll
            for (int g = 0; g < H_; ++g) S[g] += w[g * HD_] * ad;
        }
        float* bij = bias + ((size_t)bt * (V_ * V_) + i * V_ + j) * H_;
        float* bji = bias + ((size_t)bt * (V_ * V_) + j * V_ + i) * H_;
        #pragma unroll
        for (int g = 0; g < H_; ++g) {
            float lin = cL * (f_lds[j * 8 + g] - f_lds[i * 8 + g]);
            float sym = cA * S[g];
            bij[g] = lin + sym;
            bji[g] = sym - lin;
        }
    }
}

// ---------------------------------------------------------------------------
// Graph attention: per (bt, h). LDS-staged q/k/v, scores 19x19 in LDS. bf16 out.
__global__ __launch_bounds__(384) void attn_graph_kernel(
        const float* __restrict__ qkv, const float* __restrict__ bias,
        __hip_bfloat16* __restrict__ out) {
    int bt = blockIdx.x;
    int h = blockIdx.y;
    __shared__ float q_lds[V_][20];
    __shared__ float k_lds[V_][20];
    __shared__ float v_lds[V_][20];
    __shared__ float sm[V_][20];
    int tid = threadIdx.x;
    for (int idx = tid; idx < V_ * 4 * 3; idx += 384) {
        int mat = idx / (V_ * 4);
        int rem = idx - mat * (V_ * 4);
        int row = rem >> 2, part = rem & 3;
        float4 val = *reinterpret_cast<const float4*>(
            qkv + ((size_t)(bt * V_ + row)) * 384 + mat * 128 + h * DH_ + part * 4);
        float* dst = (mat == 0 ? q_lds[row] : (mat == 1 ? k_lds[row] : v_lds[row])) + part * 4;
        *reinterpret_cast<float4*>(dst) = val;
    }
    __syncthreads();
    if (tid < V_ * V_) {
        int i = tid / V_, j = tid - i * V_;
        float acc = 0.f;
        #pragma unroll
        for (int c = 0; c < 4; ++c) {
            float4 qv = *reinterpret_cast<const float4*>(&q_lds[i][4 * c]);
            float4 kv = *reinterpret_cast<const float4*>(&k_lds[j][4 * c]);
            acc += qv.x * kv.x + qv.y * kv.y + qv.z * kv.z + qv.w * kv.w;
        }
        sm[i][j] = acc * 0.25f + bias[((size_t)(bt * V_ + i) * V_ + j) * H_ + h];
    }
    __syncthreads();
    if (tid < V_) {
        float m = -1e30f;
        for (int j = 0; j < V_; ++j) m = fmaxf(m, sm[tid][j]);
        float sum = 0.f;
        for (int j = 0; j < V_; ++j) { float e = __expf(sm[tid][j] - m); sm[tid][j] = e; sum += e; }
        float inv = 1.f / sum;
        for (int j = 0; j < V_; ++j) sm[tid][j] *= inv;
    }
    __syncthreads();
    if (tid < V_ * DH_) {
        int i = tid / DH_, d = tid - i * DH_;
        float o = 0.f;
        #pragma unroll 4
        for (int j = 0; j < V_; ++j) o += sm[i][j] * v_lds[j][d];
        out[((size_t)(bt * V_ + i)) * D_ + h * DH_ + d] = __float2bfloat16(o);
    }
}

// ---------------------------------------------------------------------------
// Temporal attention: per (b, h). LDS-staged q/k/v; softmax in registers.
// Lane jt owns j = 4*jj + jt (strided): the 4 lanes of a row read CONSECUTIVE
// k rows (stride 20 floats -> disjoint bank spans, conflict-free).
__global__ __launch_bounds__(256) void attn_temporal_kernel(
        const float* __restrict__ qkv, __hip_bfloat16* __restrict__ out) {
    int b = blockIdx.x;
    int h = blockIdx.y;
    __shared__ float q_lds[T_][20];
    __shared__ float k_lds[T_][20];
    __shared__ float v_lds[T_][20];
    __shared__ float sm[T_][68];
    int tid = threadIdx.x;
    for (int idx = tid; idx < T_ * 4 * 3; idx += 256) {
        int mat = idx / (T_ * 4);
        int rem = idx - mat * (T_ * 4);
        int row = rem >> 2, part = rem & 3;
        float4 val = *reinterpret_cast<const float4*>(
            qkv + ((size_t)(b * T_ + row)) * 384 + mat * 128 + h * DH_ + part * 4);
        float* dst = (mat == 0 ? q_lds[row] : (mat == 1 ? k_lds[row] : v_lds[row])) + part * 4;
        *reinterpret_cast<float4*>(dst) = val;
    }
    __syncthreads();
    if (tid < T_ * 4) {
        int i = tid >> 2, jt = tid & 3;
        float qreg[16];
        #pragma unroll
        for (int c = 0; c < 4; ++c) {
            float4 qv = *reinterpret_cast<const float4*>(&q_lds[i][4 * c]);
            qreg[4 * c + 0] = qv.x * 0.25f;
            qreg[4 * c + 1] = qv.y * 0.25f;
            qreg[4 * c + 2] = qv.z * 0.25f;
            qreg[4 * c + 3] = qv.w * 0.25f;
        }
        float s[16];
        #pragma unroll
        for (int jj = 0; jj < 16; ++jj) {
            int j = jj * 4 + jt;
            float acc = -1e30f;
            if (j < T_) {
                acc = 0.f;
                const float* kr = k_lds[j];
                #pragma unroll
                for (int c = 0; c < 4; ++c) {
                    float4 kv = *reinterpret_cast<const float4*>(&kr[4 * c]);
                    acc += qreg[4*c+0] * kv.x + qreg[4*c+1] * kv.y
                         + qreg[4*c+2] * kv.z + qreg[4*c+3] * kv.w;
                }
            }
            s[jj] = acc;
        }
        float m = -1e30f;
        #pragma unroll
        for (int jj = 0; jj < 16; ++jj) m = fmaxf(m, s[jj]);
        m = fmaxf(m, __shfl_xor(m, 1, 64));
        m = fmaxf(m, __shfl_xor(m, 2, 64));
        float sum = 0.f;
        #pragma unroll
        for (int jj = 0; jj < 16; ++jj) {
            int j = jj * 4 + jt;
            float e = (j < T_) ? __expf(s[jj] - m) : 0.f;
            s[jj] = e;
            sum += e;
        }
        sum += __shfl_xor(sum, 1, 64);
        sum += __shfl_xor(sum, 2, 64);
        float inv = 1.f / sum;
        #pragma unroll
        for (int jj = 0; jj < 16; ++jj) {
            int j = jj * 4 + jt;
            if (j < T_) sm[i][j] = s[jj] * inv;
        }
    }
    __syncthreads();
    if (tid < T_ * 4) {
        int i = tid >> 2, dg = tid & 3;
        float4 o = {0.f, 0.f, 0.f, 0.f};
        for (int j = 0; j < T_; ++j) {
            float pp = sm[i][j];
            const float4 vv = *reinterpret_cast<const float4*>(&v_lds[j][4 * dg]);
            o.x += pp * vv.x; o.y += pp * vv.y; o.z += pp * vv.z; o.w += pp * vv.w;
        }
        bf4 ov = { __float2bfloat16(o.x), __float2bfloat16(o.y),
                   __float2bfloat16(o.z), __float2bfloat16(o.w) };
        *reinterpret_cast<bf4*>(out + ((size_t)(b * T_ + i)) * D_ + h * DH_ + 4 * dg) = ov;
    }
}

// ---------------------------------------------------------------------------
// out = LN(x + r) * g + b; optionally fp32 and/or bf16 outputs.
template<bool O32, bool O16>
__global__ __launch_bounds__(64) void ln_add_kernel(
        const float* __restrict__ x, const float* __restrict__ r,
        const float* __restrict__ g, const float* __restrict__ b,
        float* __restrict__ o32, __hip_bfloat16* __restrict__ o16) {
    int row = blockIdx.x;
    int lane = threadIdx.x;
    const float* xr = x + (size_t)row * D_;
    const float* rr = r + (size_t)row * D_;
    float v0 = xr[lane] + rr[lane];
    float v1 = xr[lane + 64] + rr[lane + 64];
    float s = v0 + v1, sq = v0 * v0 + v1 * v1;
    #pragma unroll
    for (int off = 32; off > 0; off >>= 1) {
        s += __shfl_xor(s, off, 64);
        sq += __shfl_xor(sq, off, 64);
    }
    float mean = s * (1.f / 128.f);
    float var = sq * (1.f / 128.f) - mean * mean;
    float rstd = rsqrtf(var + 1e-5f);
    float a0 = (v0 - mean) * rstd * g[lane]      + b[lane];
    float a1 = (v1 - mean) * rstd * g[lane + 64] + b[lane + 64];
    if (O32) {
        float* o = o32 + (size_t)row * D_;
        o[lane] = a0; o[lane + 64] = a1;
    }
    if (O16) {
        __hip_bfloat16* o = o16 + (size_t)row * D_;
        o[lane] = __float2bfloat16(a0); o[lane + 64] = __float2bfloat16(a1);
    }
}

// y += LN(x + r)*g + b; y_bf = bf16(y)   (fused temporal tail)
__global__ __launch_bounds__(64) void ln_add_add_kernel(
        const float* __restrict__ x, const float* __restrict__ r,
        const float* __restrict__ g, const float* __restrict__ b,
        float* __restrict__ y, __hip_bfloat16* __restrict__ y_bf) {
    int row = blockIdx.x;
    int lane = threadIdx.x;
    const float* xr = x + (size_t)row * D_;
    const float* rr = r + (size_t)row * D_;
    float v0 = xr[lane] + rr[lane];
    float v1 = xr[lane + 64] + rr[lane + 64];
    float s = v0 + v1, sq = v0 * v0 + v1 * v1;
    #pragma unroll
    for (int off = 32; off > 0; off >>= 1) {
        s += __shfl_xor(s, off, 64);
        sq += __shfl_xor(sq, off, 64);
    }
    float mean = s * (1.f / 128.f);
    float var = sq * (1.f / 128.f) - mean * mean;
    float rstd = rsqrtf(var + 1e-5f);
    float a0 = (v0 - mean) * rstd * g[lane]      + b[lane];
    float a1 = (v1 - mean) * rstd * g[lane + 64] + b[lane + 64];
    float* yp = y + (size_t)row * D_;
    __hip_bfloat16* yb = y_bf + (size_t)row * D_;
    float y0 = yp[lane] + a0;
    float y1v = yp[lane + 64] + a1;
    yp[lane] = y0;       yb[lane] = __float2bfloat16(y0);
    yp[lane + 64] = y1v; yb[lane + 64] = __float2bfloat16(y1v);
}

// ---------------------------------------------------------------------------
extern "C" void kernel_launch(void* const* d_in, const int* in_sizes, int n_in,
                              void* d_out, int out_size, void* d_ws, size_t ws_size,
                              hipStream_t stream) {
    const float* pose    = (const float*)d_in[0];
    const float* W_pose  = (const float*)d_in[1];
    const float* W_emb   = (const float*)d_in[2];
    const float* prelu_a = (const float*)d_in[3];
    const float* W_bias  = (const float*)d_in[4];
    const float* gWqkv   = (const float*)d_in[5];
    const float* gbqkv   = (const float*)d_in[6];
    const float* gWo     = (const float*)d_in[7];
    const float* gbo     = (const float*)d_in[8];
    const float* gln1g   = (const float*)d_in[9];
    const float* gln1b   = (const float*)d_in[10];
    const float* gW1     = (const float*)d_in[11];
    const float* gb1     = (const float*)d_in[12];
    const float* gW2     = (const float*)d_in[13];
    const float* gb2     = (const float*)d_in[14];
    const float* gln2g   = (const float*)d_in[15];
    const float* gln2b   = (const float*)d_in[16];
    const float* deW     = (const float*)d_in[17];
    const float* deb     = (const float*)d_in[18];
    const float* tWqkv   = (const float*)d_in[19];
    const float* tbqkv   = (const float*)d_in[20];
    const float* tWo     = (const float*)d_in[21];
    const float* tbo     = (const float*)d_in[22];
    const float* tln1g   = (const float*)d_in[23];
    const float* tln1b   = (const float*)d_in[24];
    const float* tW1     = (const float*)d_in[25];
    const float* tb1     = (const float*)d_in[26];
    const float* tW2     = (const float*)d_in[27];
    const float* tb2     = (const float*)d_in[28];
    const float* tln2g   = (const float*)d_in[29];
    const float* tln2b   = (const float*)d_in[30];
    const float* W_out   = (const float*)d_in[31];

    float* ws = (float*)d_ws;
    // workspace layout (float-slot offsets)
    __hip_bfloat16* p_bf   = (__hip_bfloat16*)(ws + 0);          // ROWS*32 bf16
    float*          y      = ws + 301568;                        // ROWS*128 f32
    __hip_bfloat16* y_bf   = (__hip_bfloat16*)(ws + 2714112);    // ROWS*128 bf16
    float*          biasbuf= ws + 3920384;                       // BT*361*8 f32
    float*          big    = ws + 6785280;                       // 7,237,632 f32
    float*          e      = big;                                // ROWS*256 f32 (pre-qkv)
    float*          qkvf   = big;                                // ROWS*384 f32
    float*          tmp    = big;                                // ROWS*128 f32 (post-attn)
    __hip_bfloat16* hid_bf = (__hip_bfloat16*)(big + 2412544);   // ROWS*256 bf16
    float*          y1     = big + 4825088;                      // ROWS*128 f32
    __hip_bfloat16* attn_bf= (__hip_bfloat16*)(ws + 14022912);   // ROWS*128 bf16
    float*          t2     = ws + 15229184;                      // ROWS*128 f32 region
    __hip_bfloat16* y1_bf  = (__hip_bfloat16*)t2;                // (phase-disjoint with t2)
    __hip_bfloat16* t2_bf  = (__hip_bfloat16*)t2;
    __hip_bfloat16* w_bf   = (__hip_bfloat16*)(ws + 17641728);   // 585,728 bf16 weights
    float*          w2     = ws + 17934592;                      // 512 f32 (Wbias@Wemb, 2 layers)
    float*          outf   = (float*)d_out;

    // bf16 weight offsets (elems)
    const int oWpose = 0, oWemb = 4096, oGqkv = 20480, oGwo = 118784, oGw1 = 151552,
              oGw2 = 217088, oDe = 282624, oTqkv = 315392, oTwo = 413696,
              oTw1 = 446464, oTw2 = 512000, oWout = 577536;

    wconv_kernel<<<(585728 + 255) / 256, 256, 0, stream>>>(
        W_pose, W_emb, gWqkv, gWo, gW1, gW2, deW, tWqkv, tWo, tW1, tW2, W_out, w_bf);
    w2_kernel<<<1, 512, 0, stream>>>(W_bias, W_emb, w2);
    transpose_kernel<<<(B_*T_*V_*C_ + 255) / 256, 256, 0, stream>>>(pose, p_bf);
    // y = p @ W_pose^T
    mfma_linear<128, 32, 0, false, true, true><<<dim3(RT_, 2), 256, 0, stream>>>(
        p_bf, w_bf + oWpose, nullptr, y, y_bf);

    for (int i = 0; i < 2; ++i) {
        // ---- graph encoder ----
        mfma_linear<256, 32, 0, false, true, false><<<dim3(RT_, 4), 256, 0, stream>>>(
            p_bf, w_bf + oWemb + i * 8192, nullptr, e, nullptr);
        bias2_kernel<<<BT_, 256, 0, stream>>>(
            e, p_bf, prelu_a + i, W_bias + (size_t)i * H_ * HD_, w2 + i * 256, biasbuf);
        mfma_linear<384, 128, 0, true, true, false><<<dim3(RT_, 6), 256, 0, stream>>>(
            y_bf, w_bf + oGqkv + i * 49152, gbqkv + (size_t)i * 384, qkvf, nullptr);
        attn_graph_kernel<<<dim3(BT_, H_), 384, 0, stream>>>(qkvf, biasbuf, attn_bf);
        mfma_linear<128, 128, 0, true, true, false><<<dim3(RT_, 2), 256, 0, stream>>>(
            attn_bf, w_bf + oGwo + i * 16384, gbo + (size_t)i * D_, tmp, nullptr);
        ln_add_kernel<true, true><<<ROWS, 64, 0, stream>>>(
            y, tmp, gln1g + (size_t)i * D_, gln1b + (size_t)i * D_, y1, y1_bf);
        mfma_linear<256, 128, 1, true, false, true><<<dim3(RT_, 4), 256, 0, stream>>>(
            y1_bf, w_bf + oGw1 + i * 32768, gb1 + (size_t)i * HD_, nullptr, hid_bf);
        mfma_linear<128, 256, 0, true, true, false><<<dim3(RT_, 2), 256, 0, stream>>>(
            hid_bf, w_bf + oGw2 + i * 32768, gb2 + (size_t)i * D_, tmp, nullptr);
        ln_add_kernel<false, true><<<ROWS, 64, 0, stream>>>(
            y1, tmp, gln2g + (size_t)i * D_, gln2b + (size_t)i * D_, nullptr, t2_bf);
        // y = de@t2 + deb + PE   (fused positional-encoding epilogue)
        mfma_linear<128, 128, 3, true, true, true><<<dim3(RT_, 2), 256, 0, stream>>>(
            t2_bf, w_bf + oDe + i * 16384, deb + (size_t)i * D_, y, y_bf);

        // ---- temporal encoder ----
        mfma_linear<384, 128, 0, true, true, false><<<dim3(RT_, 6), 256, 0, stream>>>(
            y_bf, w_bf + oTqkv + i * 49152, tbqkv + (size_t)i * 384, qkvf, nullptr);
        attn_temporal_kernel<<<dim3(BV_, H_), 256, 0, stream>>>(qkvf, attn_bf);
        mfma_linear<128, 128, 0, true, true, false><<<dim3(RT_, 2), 256, 0, stream>>>(
            attn_bf, w_bf + oTwo + i * 16384, tbo + (size_t)i * D_, tmp, nullptr);
        ln_add_kernel<true, true><<<ROWS, 64, 0, stream>>>(
            y, tmp, tln1g + (size_t)i * D_, tln1b + (size_t)i * D_, y1, y1_bf);
        mfma_linear<256, 128, 1, true, false, true><<<dim3(RT_, 4), 256, 0, stream>>>(
            y1_bf, w_bf + oTw1 + i * 32768, tb1 + (size_t)i * HD_, nullptr, hid_bf);
        mfma_linear<128, 256, 0, true, true, false><<<dim3(RT_, 2), 256, 0, stream>>>(
            hid_bf, w_bf + oTw2 + i * 32768, tb2 + (size_t)i * D_, tmp, nullptr);
        // y += LN(y1 + tmp)  (fused ln_add + add)
        ln_add_add_kernel<<<ROWS, 64, 0, stream>>>(
            y1, tmp, tln2g + (size_t)i * D_, tln2b + (size_t)i * D_, y, y_bf);
    }

    // final projection + LeakyReLU
    mfma_linear<64, 128, 2, false, true, false><<<dim3(RT_, 1), 256, 0, stream>>>(
        y_bf, w_bf + oWout, nullptr, outf, nullptr);
}

// Round 13
// 628.151 us; speedup vs baseline: 1.2526x; 1.1756x over previous
//
#include <hip/hip_runtime.h>
#include <hip/hip_bf16.h>
#include <math.h>

// Shapes (fixed by the problem)
#define B_  16
#define C_  32
#define T_  62
#define V_  19
#define D_  128
#define HD_ 256
#define H_  8
#define DH_ 16            // D_/H_
#define ROWS 18848        // B*T*V == B*V*T  (= 32*589)
#define RT32_ 589         // ROWS/32 row-tiles
#define BT_ 992           // B*T
#define BV_ 304           // B*V

typedef __attribute__((ext_vector_type(8))) short short8v;   // 8 bf16 (4 VGPRs)
typedef __attribute__((ext_vector_type(4))) float f32x4;
typedef __attribute__((ext_vector_type(16))) float f32x16;

struct alignas(8) bf4 { __hip_bfloat16 x, y, z, w; };

// ---------------------------------------------------------------------------
// pose [B,C,T,V] -> p_bf [B,T,V,C] (bf16; only consumed by bf16 GEMMs)
__global__ void transpose_kernel(const float* __restrict__ pose, __hip_bfloat16* __restrict__ p_bf) {
    int idx = blockIdx.x * 256 + threadIdx.x;
    if (idx >= B_ * T_ * V_ * C_) return;
    int c = idx & 31;
    int rest = idx >> 5;          // b*T*V + t*V + v
    int v = rest % V_;
    int rest2 = rest / V_;
    int t = rest2 % T_;
    int b = rest2 / T_;
    p_bf[idx] = __float2bfloat16(pose[((size_t)((b * C_ + c) * T_ + t)) * V_ + v]);
}

// ---------------------------------------------------------------------------
// Convert all weight matrices to bf16 into one contiguous buffer (one launch).
__global__ void wconv_kernel(
        const float* s0, const float* s1, const float* s2, const float* s3,
        const float* s4, const float* s5, const float* s6, const float* s7,
        const float* s8, const float* s9, const float* s10, const float* s11,
        __hip_bfloat16* __restrict__ dst) {
    int idx = blockIdx.x * 256 + threadIdx.x;
    if (idx >= 585728) return;
    const float* s; int base;
    if      (idx <   4096) { s = s0;  base = 0;      }
    else if (idx <  20480) { s = s1;  base = 4096;   }
    else if (idx < 118784) { s = s2;  base = 20480;  }
    else if (idx < 151552) { s = s3;  base = 118784; }
    else if (idx < 217088) { s = s4;  base = 151552; }
    else if (idx < 282624) { s = s5;  base = 217088; }
    else if (idx < 315392) { s = s6;  base = 282624; }
    else if (idx < 413696) { s = s7;  base = 315392; }
    else if (idx < 446464) { s = s8;  base = 413696; }
    else if (idx < 512000) { s = s9;  base = 446464; }
    else if (idx < 577536) { s = s10; base = 512000; }
    else                   { s = s11; base = 577536; }
    dst[idx] = __float2bfloat16(s[idx - base]);
}

// ---------------------------------------------------------------------------
// W2[layer][g][c] = sum_hh Wbias[layer,g,hh] * Wemb[layer,hh,c]   (8x32 per layer)
__global__ __launch_bounds__(512) void w2_kernel(
        const float* __restrict__ Wbias, const float* __restrict__ Wemb,
        float* __restrict__ w2) {
    int tid = threadIdx.x;
    int layer = tid >> 8, g = (tid >> 5) & 7, c = tid & 31;
    float acc = 0.f;
    for (int hh = 0; hh < HD_; ++hh)
        acc += Wbias[layer * 2048 + g * HD_ + hh] * Wemb[layer * 8192 + hh * C_ + c];
    w2[layer * 256 + g * C_ + c] = acc;
}

// ---------------------------------------------------------------------------
// MFMA linear, 32x32 tiles: out[r,n] = epi(bias[n] + sum_k A[r,k]*W[n,k]).
// mfma_f32_32x32x16_bf16: A/B lane->(row=l&31, k=(l>>5)*8+j);
// C/D: col=l&31, row=(reg&3)+8*(reg>>2)+4*(l>>5)  [guide §3, m74/m101 verified]
// grid = (RT32_, ceil(N/128)); wave w -> n-tile blockIdx.y*4+w (guard n0>=N).
// EPI: 0 none, 1 relu, 2 leaky(0.01), 3 add positional encoding
template<int N, int K, int EPI, bool HASBIAS, bool O32, bool O16>
__global__ __launch_bounds__(256) void mfma_linear(
        const __hip_bfloat16* __restrict__ A, const __hip_bfloat16* __restrict__ W,
        const float* __restrict__ bias, float* __restrict__ out32,
        __hip_bfloat16* __restrict__ out16) {
    int wave = threadIdx.x >> 6;
    int lane = threadIdx.x & 63;
    int nt = blockIdx.y * 4 + wave;
    int n0 = nt * 32;
    if (n0 >= N) return;
    int r0 = blockIdx.x * 32;
    int rl = lane & 31;
    int kk = (lane >> 5) * 8;     // 0 or 8
    const short* Ab = (const short*)A + (size_t)(r0 + rl) * K + kk;
    const short* Wb = (const short*)W + (size_t)(n0 + rl) * K + kk;
    f32x16 acc = {0.f,0.f,0.f,0.f,0.f,0.f,0.f,0.f,0.f,0.f,0.f,0.f,0.f,0.f,0.f,0.f};
    #pragma unroll
    for (int kb = 0; kb < K / 16; ++kb) {
        short8v a = *reinterpret_cast<const short8v*>(Ab + kb * 16);
        short8v b = *reinterpret_cast<const short8v*>(Wb + kb * 16);
        acc = __builtin_amdgcn_mfma_f32_32x32x16_bf16(a, b, acc, 0, 0, 0);
    }
    int oc = n0 + rl;
    float bv = HASBIAS ? bias[oc] : 0.f;
    float freq = 0.f;
    if (EPI == 3) freq = expf(-(float)(oc & ~1) * (9.210340371976184f / 128.f));
    #pragma unroll
    for (int reg = 0; reg < 16; ++reg) {
        int orow = r0 + (reg & 3) + 8 * (reg >> 2) + 4 * (lane >> 5);
        float v = acc[reg] + bv;
        if (EPI == 1) v = fmaxf(v, 0.f);
        if (EPI == 2) v = v >= 0.f ? v : 0.01f * v;
        if (EPI == 3) {
            int t = orow % T_;
            float ang = (float)t * freq;
            v += (oc & 1) ? cosf(ang) : sinf(ang);
        }
        if (O32) out32[(size_t)orow * N + oc] = v;
        if (O16) out16[(size_t)orow * N + oc] = __float2bfloat16(v);
    }
}

// ---------------------------------------------------------------------------
// bias2 v4: e computed IN-BLOCK (e = p@Wemb^T only feeds this kernel).
// prelu(x) = cL*x + cA*|x|; linear term telescopes via f = p@W2^T (W2=Wbias@Wemb);
// |d| term symmetric -> 190 upper-tri pairs. es stride 257 (conflict-free scalar).
__global__ __launch_bounds__(256) void bias2_kernel(
        const __hip_bfloat16* __restrict__ p_bf, const __hip_bfloat16* __restrict__ wemb_bf,
        const float* __restrict__ prelu_a, const float* __restrict__ Wbias,
        const float* __restrict__ w2, float* __restrict__ bias) {
    int bt = blockIdx.x;
    __shared__ float es[V_ * 257];
    __shared__ float ps[V_ * 33];
    __shared__ float f_lds[V_ * 8];
    int tid = threadIdx.x;
    // stage p (19x32 bf16 -> f32)
    if (tid < V_ * 8) {
        int v = tid >> 3, c4 = (tid & 7) * 4;
        bf4 pv = *reinterpret_cast<const bf4*>(&p_bf[((size_t)(bt * V_ + v)) * C_ + c4]);
        float* d = &ps[v * 33 + c4];
        d[0] = __bfloat162float(pv.x); d[1] = __bfloat162float(pv.y);
        d[2] = __bfloat162float(pv.z); d[3] = __bfloat162float(pv.w);
    }
    __syncthreads();
    // compute e rows: thread tid owns embedding dim hh=tid for all 19 vertices
    {
        float wr[C_];
        const __hip_bfloat16* wrow = wemb_bf + (size_t)tid * C_;
        #pragma unroll
        for (int c4 = 0; c4 < 8; ++c4) {
            bf4 wv = *reinterpret_cast<const bf4*>(wrow + c4 * 4);
            wr[c4 * 4 + 0] = __bfloat162float(wv.x);
            wr[c4 * 4 + 1] = __bfloat162float(wv.y);
            wr[c4 * 4 + 2] = __bfloat162float(wv.z);
            wr[c4 * 4 + 3] = __bfloat162float(wv.w);
        }
        for (int v = 0; v < V_; ++v) {
            const float* pr = &ps[v * 33];
            float acc = 0.f;
            #pragma unroll
            for (int c = 0; c < C_; ++c) acc += pr[c] * wr[c];
            es[v * 257 + tid] = acc;
        }
    }
    // f[v,g] = ps[v,:] . w2[g,:]  (K=32)
    if (tid < V_ * 8) {
        int v = tid >> 3, g = tid & 7;
        const float* pr = &ps[v * 33];
        const float* wr = &w2[g * C_];
        float acc = 0.f;
        #pragma unroll
        for (int c = 0; c < C_; ++c) acc += pr[c] * wr[c];
        f_lds[v * 8 + g] = acc;
    }
    __syncthreads();
    // phase 2: 190 upper-tri pairs
    if (tid < 190) {
        int i = 0, rem = tid, cnt = V_;
        while (rem >= cnt) { rem -= cnt; ++i; --cnt; }
        int j = i + rem;                       // i <= j
        const float a = prelu_a[0];
        const float scale = 0.35355339059327373f;   // 1/sqrt(8)
        const float cL = 0.5f * (1.f + a) * scale;
        const float cA = 0.5f * (1.f - a) * scale;
        const float* ei = es + i * 257;
        const float* ej = es + j * 257;
        float S[H_] = {0.f, 0.f, 0.f, 0.f, 0.f, 0.f, 0.f, 0.f};
        #pragma unroll 4
        for (int hh = 0; hh < HD_; ++hh) {
            float d = ej[hh] - ei[hh];
            float ad = fabsf(d);
            const float* w = Wbias + hh;       // block-uniform -> s_load
            #pragma unroll
            for (int g = 0; g < H_; ++g) S[g] += w[g * HD_] * ad;
        }
        float* bij = bias + ((size_t)bt * (V_ * V_) + i * V_ + j) * H_;
        float* bji = bias + ((size_t)bt * (V_ * V_) + j * V_ + i) * H_;
        #pragma unroll
        for (int g = 0; g < H_; ++g) {
            float lin = cL * (f_lds[j * 8 + g] - f_lds[i * 8 + g]);
            float sym = cA * S[g];
            bij[g] = lin + sym;
            bji[g] = sym - lin;
        }
    }
}

// ---------------------------------------------------------------------------
// Graph attention: per (bt, h). LDS-staged q/k/v, scores 19x19 in LDS. bf16 out.
__global__ __launch_bounds__(384) void attn_graph_kernel(
        const float* __restrict__ qkv, const float* __restrict__ bias,
        __hip_bfloat16* __restrict__ out) {
    int bt = blockIdx.x;
    int h = blockIdx.y;
    __shared__ float q_lds[V_][20];
    __shared__ float k_lds[V_][20];
    __shared__ float v_lds[V_][20];
    __shared__ float sm[V_][20];
    int tid = threadIdx.x;
    for (int idx = tid; idx < V_ * 4 * 3; idx += 384) {
        int mat = idx / (V_ * 4);
        int rem = idx - mat * (V_ * 4);
        int row = rem >> 2, part = rem & 3;
        float4 val = *reinterpret_cast<const float4*>(
            qkv + ((size_t)(bt * V_ + row)) * 384 + mat * 128 + h * DH_ + part * 4);
        float* dst = (mat == 0 ? q_lds[row] : (mat == 1 ? k_lds[row] : v_lds[row])) + part * 4;
        *reinterpret_cast<float4*>(dst) = val;
    }
    __syncthreads();
    if (tid < V_ * V_) {
        int i = tid / V_, j = tid - i * V_;
        float acc = 0.f;
        #pragma unroll
        for (int c = 0; c < 4; ++c) {
            float4 qv = *reinterpret_cast<const float4*>(&q_lds[i][4 * c]);
            float4 kv = *reinterpret_cast<const float4*>(&k_lds[j][4 * c]);
            acc += qv.x * kv.x + qv.y * kv.y + qv.z * kv.z + qv.w * kv.w;
        }
        sm[i][j] = acc * 0.25f + bias[((size_t)(bt * V_ + i) * V_ + j) * H_ + h];
    }
    __syncthreads();
    if (tid < V_) {
        float m = -1e30f;
        for (int j = 0; j < V_; ++j) m = fmaxf(m, sm[tid][j]);
        float sum = 0.f;
        for (int j = 0; j < V_; ++j) { float e = __expf(sm[tid][j] - m); sm[tid][j] = e; sum += e; }
        float inv = 1.f / sum;
        for (int j = 0; j < V_; ++j) sm[tid][j] *= inv;
    }
    __syncthreads();
    if (tid < V_ * DH_) {
        int i = tid / DH_, d = tid - i * DH_;
        float o = 0.f;
        #pragma unroll 4
        for (int j = 0; j < V_; ++j) o += sm[i][j] * v_lds[j][d];
        out[((size_t)(bt * V_ + i)) * D_ + h * DH_ + d] = __float2bfloat16(o);
    }
}

// ---------------------------------------------------------------------------
// Temporal attention: per (b, h). LDS-staged q/k/v; softmax in registers.
// Lane jt owns j = 4*jj + jt (strided): conflict-free k reads.
__global__ __launch_bounds__(256) void attn_temporal_kernel(
        const float* __restrict__ qkv, __hip_bfloat16* __restrict__ out) {
    int b = blockIdx.x;
    int h = blockIdx.y;
    __shared__ float q_lds[T_][20];
    __shared__ float k_lds[T_][20];
    __shared__ float v_lds[T_][20];
    __shared__ float sm[T_][68];
    int tid = threadIdx.x;
    for (int idx = tid; idx < T_ * 4 * 3; idx += 256) {
        int mat = idx / (T_ * 4);
        int rem = idx - mat * (T_ * 4);
        int row = rem >> 2, part = rem & 3;
        float4 val = *reinterpret_cast<const float4*>(
            qkv + ((size_t)(b * T_ + row)) * 384 + mat * 128 + h * DH_ + part * 4);
        float* dst = (mat == 0 ? q_lds[row] : (mat == 1 ? k_lds[row] : v_lds[row])) + part * 4;
        *reinterpret_cast<float4*>(dst) = val;
    }
    __syncthreads();
    if (tid < T_ * 4) {
        int i = tid >> 2, jt = tid & 3;
        float qreg[16];
        #pragma unroll
        for (int c = 0; c < 4; ++c) {
            float4 qv = *reinterpret_cast<const float4*>(&q_lds[i][4 * c]);
            qreg[4 * c + 0] = qv.x * 0.25f;
            qreg[4 * c + 1] = qv.y * 0.25f;
            qreg[4 * c + 2] = qv.z * 0.25f;
            qreg[4 * c + 3] = qv.w * 0.25f;
        }
        float s[16];
        #pragma unroll
        for (int jj = 0; jj < 16; ++jj) {
            int j = jj * 4 + jt;
            float acc = -1e30f;
            if (j < T_) {
                acc = 0.f;
                const float* kr = k_lds[j];
                #pragma unroll
                for (int c = 0; c < 4; ++c) {
                    float4 kv = *reinterpret_cast<const float4*>(&kr[4 * c]);
                    acc += qreg[4*c+0] * kv.x + qreg[4*c+1] * kv.y
                         + qreg[4*c+2] * kv.z + qreg[4*c+3] * kv.w;
                }
            }
            s[jj] = acc;
        }
        float m = -1e30f;
        #pragma unroll
        for (int jj = 0; jj < 16; ++jj) m = fmaxf(m, s[jj]);
        m = fmaxf(m, __shfl_xor(m, 1, 64));
        m = fmaxf(m, __shfl_xor(m, 2, 64));
        float sum = 0.f;
        #pragma unroll
        for (int jj = 0; jj < 16; ++jj) {
            int j = jj * 4 + jt;
            float e = (j < T_) ? __expf(s[jj] - m) : 0.f;
            s[jj] = e;
            sum += e;
        }
        sum += __shfl_xor(sum, 1, 64);
        sum += __shfl_xor(sum, 2, 64);
        float inv = 1.f / sum;
        #pragma unroll
        for (int jj = 0; jj < 16; ++jj) {
            int j = jj * 4 + jt;
            if (j < T_) sm[i][j] = s[jj] * inv;
        }
    }
    __syncthreads();
    if (tid < T_ * 4) {
        int i = tid >> 2, dg = tid & 3;
        float4 o = {0.f, 0.f, 0.f, 0.f};
        for (int j = 0; j < T_; ++j) {
            float pp = sm[i][j];
            const float4 vv = *reinterpret_cast<const float4*>(&v_lds[j][4 * dg]);
            o.x += pp * vv.x; o.y += pp * vv.y; o.z += pp * vv.z; o.w += pp * vv.w;
        }
        bf4 ov = { __float2bfloat16(o.x), __float2bfloat16(o.y),
                   __float2bfloat16(o.z), __float2bfloat16(o.w) };
        *reinterpret_cast<bf4*>(out + ((size_t)(b * T_ + i)) * D_ + h * DH_ + 4 * dg) = ov;
    }
}

// ---------------------------------------------------------------------------
// out = LN(x + r) * g + b; optionally fp32 and/or bf16 outputs.
template<bool O32, bool O16>
__global__ __launch_bounds__(64) void ln_add_kernel(
        const float* __restrict__ x, const float* __restrict__ r,
        const float* __restrict__ g, const float* __restrict__ b,
        float* __restrict__ o32, __hip_bfloat16* __restrict__ o16) {
    int row = blockIdx.x;
    int lane = threadIdx.x;
    const float* xr = x + (size_t)row * D_;
    const float* rr = r + (size_t)row * D_;
    float v0 = xr[lane] + rr[lane];
    float v1 = xr[lane + 64] + rr[lane + 64];
    float s = v0 + v1, sq = v0 * v0 + v1 * v1;
    #pragma unroll
    for (int off = 32; off > 0; off >>= 1) {
        s += __shfl_xor(s, off, 64);
        sq += __shfl_xor(sq, off, 64);
    }
    float mean = s * (1.f / 128.f);
    float var = sq * (1.f / 128.f) - mean * mean;
    float rstd = rsqrtf(var + 1e-5f);
    float a0 = (v0 - mean) * rstd * g[lane]      + b[lane];
    float a1 = (v1 - mean) * rstd * g[lane + 64] + b[lane + 64];
    if (O32) {
        float* o = o32 + (size_t)row * D_;
        o[lane] = a0; o[lane + 64] = a1;
    }
    if (O16) {
        __hip_bfloat16* o = o16 + (size_t)row * D_;
        o[lane] = __float2bfloat16(a0); o[lane + 64] = __float2bfloat16(a1);
    }
}

// y += LN(x + r)*g + b; y_bf = bf16(y)   (fused temporal tail)
__global__ __launch_bounds__(64) void ln_add_add_kernel(
        const float* __restrict__ x, const float* __restrict__ r,
        const float* __restrict__ g, const float* __restrict__ b,
        float* __restrict__ y, __hip_bfloat16* __restrict__ y_bf) {
    int row = blockIdx.x;
    int lane = threadIdx.x;
    const float* xr = x + (size_t)row * D_;
    const float* rr = r + (size_t)row * D_;
    float v0 = xr[lane] + rr[lane];
    float v1 = xr[lane + 64] + rr[lane + 64];
    float s = v0 + v1, sq = v0 * v0 + v1 * v1;
    #pragma unroll
    for (int off = 32; off > 0; off >>= 1) {
        s += __shfl_xor(s, off, 64);
        sq += __shfl_xor(sq, off, 64);
    }
    float mean = s * (1.f / 128.f);
    float var = sq * (1.f / 128.f) - mean * mean;
    float rstd = rsqrtf(var + 1e-5f);
    float a0 = (v0 - mean) * rstd * g[lane]      + b[lane];
    float a1 = (v1 - mean) * rstd * g[lane + 64] + b[lane + 64];
    float* yp = y + (size_t)row * D_;
    __hip_bfloat16* yb = y_bf + (size_t)row * D_;
    float y0 = yp[lane] + a0;
    float y1v = yp[lane + 64] + a1;
    yp[lane] = y0;       yb[lane] = __float2bfloat16(y0);
    yp[lane + 64] = y1v; yb[lane + 64] = __float2bfloat16(y1v);
}

// ---------------------------------------------------------------------------
extern "C" void kernel_launch(void* const* d_in, const int* in_sizes, int n_in,
                              void* d_out, int out_size, void* d_ws, size_t ws_size,
                              hipStream_t stream) {
    const float* pose    = (const float*)d_in[0];
    const float* W_pose  = (const float*)d_in[1];
    const float* W_emb   = (const float*)d_in[2];
    const float* prelu_a = (const float*)d_in[3];
    const float* W_bias  = (const float*)d_in[4];
    const float* gWqkv   = (const float*)d_in[5];
    const float* gbqkv   = (const float*)d_in[6];
    const float* gWo     = (const float*)d_in[7];
    const float* gbo     = (const float*)d_in[8];
    const float* gln1g   = (const float*)d_in[9];
    const float* gln1b   = (const float*)d_in[10];
    const float* gW1     = (const float*)d_in[11];
    const float* gb1     = (const float*)d_in[12];
    const float* gW2     = (const float*)d_in[13];
    const float* gb2     = (const float*)d_in[14];
    const float* gln2g   = (const float*)d_in[15];
    const float* gln2b   = (const float*)d_in[16];
    const float* deW     = (const float*)d_in[17];
    const float* deb     = (const float*)d_in[18];
    const float* tWqkv   = (const float*)d_in[19];
    const float* tbqkv   = (const float*)d_in[20];
    const float* tWo     = (const float*)d_in[21];
    const float* tbo     = (const float*)d_in[22];
    const float* tln1g   = (const float*)d_in[23];
    const float* tln1b   = (const float*)d_in[24];
    const float* tW1     = (const float*)d_in[25];
    const float* tb1     = (const float*)d_in[26];
    const float* tW2     = (const float*)d_in[27];
    const float* tb2     = (const float*)d_in[28];
    const float* tln2g   = (const float*)d_in[29];
    const float* tln2b   = (const float*)d_in[30];
    const float* W_out   = (const float*)d_in[31];

    float* ws = (float*)d_ws;
    // workspace layout (float-slot offsets)
    __hip_bfloat16* p_bf   = (__hip_bfloat16*)(ws + 0);          // ROWS*32 bf16
    float*          y      = ws + 301568;                        // ROWS*128 f32
    __hip_bfloat16* y_bf   = (__hip_bfloat16*)(ws + 2714112);    // ROWS*128 bf16
    float*          biasbuf= ws + 3920384;                       // BT*361*8 f32
    float*          big    = ws + 6785280;                       // 7,237,632 f32
    float*          qkvf   = big;                                // ROWS*384 f32
    float*          tmp    = big;                                // ROWS*128 f32 (post-attn)
    __hip_bfloat16* hid_bf = (__hip_bfloat16*)(big + 2412544);   // ROWS*256 bf16
    float*          y1     = big + 4825088;                      // ROWS*128 f32
    __hip_bfloat16* attn_bf= (__hip_bfloat16*)(ws + 14022912);   // ROWS*128 bf16
    float*          t2     = ws + 15229184;                      // ROWS*128 f32 region
    __hip_bfloat16* y1_bf  = (__hip_bfloat16*)t2;                // (phase-disjoint with t2)
    __hip_bfloat16* t2_bf  = (__hip_bfloat16*)t2;
    __hip_bfloat16* w_bf   = (__hip_bfloat16*)(ws + 17641728);   // 585,728 bf16 weights
    float*          w2     = ws + 17934592;                      // 512 f32 (Wbias@Wemb, 2 layers)
    float*          outf   = (float*)d_out;

    // bf16 weight offsets (elems)
    const int oWpose = 0, oWemb = 4096, oGqkv = 20480, oGwo = 118784, oGw1 = 151552,
              oGw2 = 217088, oDe = 282624, oTqkv = 315392, oTwo = 413696,
              oTw1 = 446464, oTw2 = 512000, oWout = 577536;

    wconv_kernel<<<(585728 + 255) / 256, 256, 0, stream>>>(
        W_pose, W_emb, gWqkv, gWo, gW1, gW2, deW, tWqkv, tWo, tW1, tW2, W_out, w_bf);
    w2_kernel<<<1, 512, 0, stream>>>(W_bias, W_emb, w2);
    transpose_kernel<<<(B_*T_*V_*C_ + 255) / 256, 256, 0, stream>>>(pose, p_bf);
    // y = p @ W_pose^T
    mfma_linear<128, 32, 0, false, true, true><<<dim3(RT32_, 1), 256, 0, stream>>>(
        p_bf, w_bf + oWpose, nullptr, y, y_bf);

    for (int i = 0; i < 2; ++i) {
        // ---- graph encoder ----
        bias2_kernel<<<BT_, 256, 0, stream>>>(
            p_bf, w_bf + oWemb + i * 8192, prelu_a + i,
            W_bias + (size_t)i * H_ * HD_, w2 + i * 256, biasbuf);
        mfma_linear<384, 128, 0, true, true, false><<<dim3(RT32_, 3), 256, 0, stream>>>(
            y_bf, w_bf + oGqkv + i * 49152, gbqkv + (size_t)i * 384, qkvf, nullptr);
        attn_graph_kernel<<<dim3(BT_, H_), 384, 0, stream>>>(qkvf, biasbuf, attn_bf);
        mfma_linear<128, 128, 0, true, true, false><<<dim3(RT32_, 1), 256, 0, stream>>>(
            attn_bf, w_bf + oGwo + i * 16384, gbo + (size_t)i * D_, tmp, nullptr);
        ln_add_kernel<true, true><<<ROWS, 64, 0, stream>>>(
            y, tmp, gln1g + (size_t)i * D_, gln1b + (size_t)i * D_, y1, y1_bf);
        mfma_linear<256, 128, 1, true, false, true><<<dim3(RT32_, 2), 256, 0, stream>>>(
            y1_bf, w_bf + oGw1 + i * 32768, gb1 + (size_t)i * HD_, nullptr, hid_bf);
        mfma_linear<128, 256, 0, true, true, false><<<dim3(RT32_, 1), 256, 0, stream>>>(
            hid_bf, w_bf + oGw2 + i * 32768, gb2 + (size_t)i * D_, tmp, nullptr);
        ln_add_kernel<false, true><<<ROWS, 64, 0, stream>>>(
            y1, tmp, gln2g + (size_t)i * D_, gln2b + (size_t)i * D_, nullptr, t2_bf);
        // y = de@t2 + deb + PE   (fused positional-encoding epilogue)
        mfma_linear<128, 128, 3, true, true, true><<<dim3(RT32_, 1), 256, 0, stream>>>(
            t2_bf, w_bf + oDe + i * 16384, deb + (size_t)i * D_, y, y_bf);

        // ---- temporal encoder ----
        mfma_linear<384, 128, 0, true, true, false><<<dim3(RT32_, 3), 256, 0, stream>>>(
            y_bf, w_bf + oTqkv + i * 49152, tbqkv + (size_t)i * 384, qkvf, nullptr);
        attn_temporal_kernel<<<dim3(BV_, H_), 256, 0, stream>>>(qkvf, attn_bf);
        mfma_linear<128, 128, 0, true, true, false><<<dim3(RT32_, 1), 256, 0, stream>>>(
            attn_bf, w_bf + oTwo + i * 16384, tbo + (size_t)i * D_, tmp, nullptr);
        ln_add_kernel<true, true><<<ROWS, 64, 0, stream>>>(
            y, tmp, tln1g + (size_t)i * D_, tln1b + (size_t)i * D_, y1, y1_bf);
        mfma_linear<256, 128, 1, true, false, true><<<dim3(RT32_, 2), 256, 0, stream>>>(
            y1_bf, w_bf + oTw1 + i * 32768, tb1 + (size_t)i * HD_, nullptr, hid_bf);
        mfma_linear<128, 256, 0, true, true, false><<<dim3(RT32_, 1), 256, 0, stream>>>(
            hid_bf, w_bf + oTw2 + i * 32768, tb2 + (size_t)i * D_, tmp, nullptr);
        // y += LN(y1 + tmp)  (fused ln_add + add)
        ln_add_add_kernel<<<ROWS, 64, 0, stream>>>(
            y1, tmp, tln2g + (size_t)i * D_, tln2b + (size_t)i * D_, y, y_bf);
    }

    // final projection + LeakyReLU
    mfma_linear<64, 128, 2, false, true, false><<<dim3(RT32_, 1), 256, 0, stream>>>(
        y_bf, w_bf + oWout, nullptr, outf, nullptr);
}

// Round 14
// 626.799 us; speedup vs baseline: 1.2553x; 1.0022x over previous
//
#include <hip/hip_runtime.h>
#include <hip/hip_bf16.h>
#include <math.h>

// Shapes (fixed by the problem)
#define B_  16
#define C_  32
#define T_  62
#define V_  19
#define D_  128
#define HD_ 256
#define H_  8
#define DH_ 16            // D_/H_
#define ROWS 18848        // B*T*V == B*V*T  (= 32*589)
#define BT_ 992           // B*T
#define BV_ 304           // B*V

typedef __attribute__((ext_vector_type(8))) short short8v;   // 8 bf16 (4 VGPRs)
typedef __attribute__((ext_vector_type(4))) float f32x4;
typedef __attribute__((ext_vector_type(16))) float f32x16;

struct alignas(8) bf4 { __hip_bfloat16 x, y, z, w; };

__device__ __forceinline__ float bf2f(short s) {
    return __uint_as_float(((unsigned)(unsigned short)s) << 16);
}

// ---------------------------------------------------------------------------
// pose [B,C,T,V] -> p_bf [B,T,V,C] (bf16; only consumed by bf16 GEMMs)
__global__ void transpose_kernel(const float* __restrict__ pose, __hip_bfloat16* __restrict__ p_bf) {
    int idx = blockIdx.x * 256 + threadIdx.x;
    if (idx >= B_ * T_ * V_ * C_) return;
    int c = idx & 31;
    int rest = idx >> 5;          // b*T*V + t*V + v
    int v = rest % V_;
    int rest2 = rest / V_;
    int t = rest2 % T_;
    int b = rest2 / T_;
    p_bf[idx] = __float2bfloat16(pose[((size_t)((b * C_ + c) * T_ + t)) * V_ + v]);
}

// ---------------------------------------------------------------------------
// Convert all weight matrices to bf16 into one contiguous buffer (one launch).
__global__ void wconv_kernel(
        const float* s0, const float* s1, const float* s2, const float* s3,
        const float* s4, const float* s5, const float* s6, const float* s7,
        const float* s8, const float* s9, const float* s10, const float* s11,
        __hip_bfloat16* __restrict__ dst) {
    int idx = blockIdx.x * 256 + threadIdx.x;
    if (idx >= 585728) return;
    const float* s; int base;
    if      (idx <   4096) { s = s0;  base = 0;      }
    else if (idx <  20480) { s = s1;  base = 4096;   }
    else if (idx < 118784) { s = s2;  base = 20480;  }
    else if (idx < 151552) { s = s3;  base = 118784; }
    else if (idx < 217088) { s = s4;  base = 151552; }
    else if (idx < 282624) { s = s5;  base = 217088; }
    else if (idx < 315392) { s = s6;  base = 282624; }
    else if (idx < 413696) { s = s7;  base = 315392; }
    else if (idx < 446464) { s = s8;  base = 413696; }
    else if (idx < 512000) { s = s9;  base = 446464; }
    else if (idx < 577536) { s = s10; base = 512000; }
    else                   { s = s11; base = 577536; }
    dst[idx] = __float2bfloat16(s[idx - base]);
}

// ---------------------------------------------------------------------------
// W2[layer][g][c] = sum_hh Wbias[layer,g,hh] * Wemb[layer,hh,c]   (8x32 per layer)
__global__ __launch_bounds__(512) void w2_kernel(
        const float* __restrict__ Wbias, const float* __restrict__ Wemb,
        float* __restrict__ w2) {
    int tid = threadIdx.x;
    int layer = tid >> 8, g = (tid >> 5) & 7, c = tid & 31;
    float acc = 0.f;
    for (int hh = 0; hh < HD_; ++hh)
        acc += Wbias[layer * 2048 + g * HD_ + hh] * Wemb[layer * 8192 + hh * C_ + c];
    w2[layer * 256 + g * C_ + c] = acc;
}

// ---------------------------------------------------------------------------
// MFMA linear, 32x32 tiles, 2 ROW-TILES PER WAVE (B-fragment reuse).
// mfma_f32_32x32x16_bf16: A/B lane->(row=l&31, k=(l>>5)*8+j);
// C/D: col=l&31, row=(reg&3)+8*(reg>>2)+4*(l>>5)  [guide §3, m74/m101 verified]
// grid = ((ROWS+63)/64, ceil(N/128)); wave w -> n-tile blockIdx.y*4+w.
// EPI: 0 none, 1 relu, 2 leaky(0.01), 3 add positional encoding
template<int N, int K, int EPI, bool HASBIAS, bool O32, bool O16>
__global__ __launch_bounds__(256) void mfma_linear(
        const __hip_bfloat16* __restrict__ A, const __hip_bfloat16* __restrict__ W,
        const float* __restrict__ bias, float* __restrict__ out32,
        __hip_bfloat16* __restrict__ out16) {
    int wave = threadIdx.x >> 6;
    int lane = threadIdx.x & 63;
    int nt = blockIdx.y * 4 + wave;
    int n0 = nt * 32;
    if (n0 >= N) return;
    int r0 = blockIdx.x * 64;
    int r1 = r0 + 32;
    bool has2 = (r1 < ROWS);
    int rl = lane & 31;
    int kk = (lane >> 5) * 8;     // 0 or 8
    const short* Ab0 = (const short*)A + (size_t)(r0 + rl) * K + kk;
    const short* Ab1 = (const short*)A + (size_t)(r1 + rl) * K + kk;
    const short* Wb  = (const short*)W + (size_t)(n0 + rl) * K + kk;
    f32x16 acc0 = {0.f,0.f,0.f,0.f,0.f,0.f,0.f,0.f,0.f,0.f,0.f,0.f,0.f,0.f,0.f,0.f};
    f32x16 acc1 = acc0;
    #pragma unroll
    for (int kb = 0; kb < K / 16; ++kb) {
        short8v b  = *reinterpret_cast<const short8v*>(Wb  + kb * 16);
        short8v a0 = *reinterpret_cast<const short8v*>(Ab0 + kb * 16);
        acc0 = __builtin_amdgcn_mfma_f32_32x32x16_bf16(a0, b, acc0, 0, 0, 0);
        if (has2) {
            short8v a1 = *reinterpret_cast<const short8v*>(Ab1 + kb * 16);
            acc1 = __builtin_amdgcn_mfma_f32_32x32x16_bf16(a1, b, acc1, 0, 0, 0);
        }
    }
    int oc = n0 + rl;
    float bv = HASBIAS ? bias[oc] : 0.f;
    float freq = 0.f;
    if (EPI == 3) freq = expf(-(float)(oc & ~1) * (9.210340371976184f / 128.f));
    #pragma unroll
    for (int t2 = 0; t2 < 2; ++t2) {
        if (t2 == 1 && !has2) break;
        int rb = t2 ? r1 : r0;
        f32x16 acc = t2 ? acc1 : acc0;
        #pragma unroll
        for (int reg = 0; reg < 16; ++reg) {
            int orow = rb + (reg & 3) + 8 * (reg >> 2) + 4 * (lane >> 5);
            float v = acc[reg] + bv;
            if (EPI == 1) v = fmaxf(v, 0.f);
            if (EPI == 2) v = v >= 0.f ? v : 0.01f * v;
            if (EPI == 3) {
                int t = orow % T_;
                float ang = (float)t * freq;
                v += (oc & 1) ? cosf(ang) : sinf(ang);
            }
            if (O32) out32[(size_t)orow * N + oc] = v;
            if (O16) out16[(size_t)orow * N + oc] = __float2bfloat16(v);
        }
    }
}

// ---------------------------------------------------------------------------
// bias2 v4: e computed IN-BLOCK (e = p@Wemb^T only feeds this kernel).
// prelu(x) = cL*x + cA*|x|; linear term telescopes via f = p@W2^T (W2=Wbias@Wemb);
// |d| term symmetric -> 190 upper-tri pairs. es stride 257 (conflict-free scalar).
__global__ __launch_bounds__(256) void bias2_kernel(
        const __hip_bfloat16* __restrict__ p_bf, const __hip_bfloat16* __restrict__ wemb_bf,
        const float* __restrict__ prelu_a, const float* __restrict__ Wbias,
        const float* __restrict__ w2, float* __restrict__ bias) {
    int bt = blockIdx.x;
    __shared__ float es[V_ * 257];
    __shared__ float ps[V_ * 33];
    __shared__ float f_lds[V_ * 8];
    int tid = threadIdx.x;
    // stage p (19x32 bf16 -> f32)
    if (tid < V_ * 8) {
        int v = tid >> 3, c4 = (tid & 7) * 4;
        bf4 pv = *reinterpret_cast<const bf4*>(&p_bf[((size_t)(bt * V_ + v)) * C_ + c4]);
        float* d = &ps[v * 33 + c4];
        d[0] = __bfloat162float(pv.x); d[1] = __bfloat162float(pv.y);
        d[2] = __bfloat162float(pv.z); d[3] = __bfloat162float(pv.w);
    }
    __syncthreads();
    // compute e rows: thread tid owns embedding dim hh=tid for all 19 vertices
    {
        float wr[C_];
        const __hip_bfloat16* wrow = wemb_bf + (size_t)tid * C_;
        #pragma unroll
        for (int c4 = 0; c4 < 8; ++c4) {
            bf4 wv = *reinterpret_cast<const bf4*>(wrow + c4 * 4);
            wr[c4 * 4 + 0] = __bfloat162float(wv.x);
            wr[c4 * 4 + 1] = __bfloat162float(wv.y);
            wr[c4 * 4 + 2] = __bfloat162float(wv.z);
            wr[c4 * 4 + 3] = __bfloat162float(wv.w);
        }
        for (int v = 0; v < V_; ++v) {
            const float* pr = &ps[v * 33];
            float acc = 0.f;
            #pragma unroll
            for (int c = 0; c < C_; ++c) acc += pr[c] * wr[c];
            es[v * 257 + tid] = acc;
        }
    }
    // f[v,g] = ps[v,:] . w2[g,:]  (K=32)
    if (tid < V_ * 8) {
        int v = tid >> 3, g = tid & 7;
        const float* pr = &ps[v * 33];
        const float* wr = &w2[g * C_];
        float acc = 0.f;
        #pragma unroll
        for (int c = 0; c < C_; ++c) acc += pr[c] * wr[c];
        f_lds[v * 8 + g] = acc;
    }
    __syncthreads();
    // phase 2: 190 upper-tri pairs
    if (tid < 190) {
        int i = 0, rem = tid, cnt = V_;
        while (rem >= cnt) { rem -= cnt; ++i; --cnt; }
        int j = i + rem;                       // i <= j
        const float a = prelu_a[0];
        const float scale = 0.35355339059327373f;   // 1/sqrt(8)
        const float cL = 0.5f * (1.f + a) * scale;
        const float cA = 0.5f * (1.f - a) * scale;
        const float* ei = es + i * 257;
        const float* ej = es + j * 257;
        float S[H_] = {0.f, 0.f, 0.f, 0.f, 0.f, 0.f, 0.f, 0.f};
        #pragma unroll 4
        for (int hh = 0; hh < HD_; ++hh) {
            float d = ej[hh] - ei[hh];
            float ad = fabsf(d);
            const float* w = Wbias + hh;       // block-uniform -> s_load
            #pragma unroll
            for (int g = 0; g < H_; ++g) S[g] += w[g * HD_] * ad;
        }
        float* bij = bias + ((size_t)bt * (V_ * V_) + i * V_ + j) * H_;
        float* bji = bias + ((size_t)bt * (V_ * V_) + j * V_ + i) * H_;
        #pragma unroll
        for (int g = 0; g < H_; ++g) {
            float lin = cL * (f_lds[j * 8 + g] - f_lds[i * 8 + g]);
            float sym = cA * S[g];
            bij[g] = lin + sym;
            bji[g] = sym - lin;
        }
    }
}

// ---------------------------------------------------------------------------
// Graph attention: per (bt, h). bf16 qkv staged to f32 LDS. bf16 out.
__global__ __launch_bounds__(384) void attn_graph_kernel(
        const __hip_bfloat16* __restrict__ qkv, const float* __restrict__ bias,
        __hip_bfloat16* __restrict__ out) {
    int bt = blockIdx.x;
    int h = blockIdx.y;
    __shared__ float q_lds[V_][20];
    __shared__ float k_lds[V_][20];
    __shared__ float v_lds[V_][20];
    __shared__ float sm[V_][20];
    int tid = threadIdx.x;
    // stage: 19 rows x 2 halves x 3 matrices = 114 chunks of 8 bf16 (16B loads)
    for (int idx = tid; idx < V_ * 2 * 3; idx += 384) {
        int mat = idx / (V_ * 2);
        int rem = idx - mat * (V_ * 2);
        int row = rem >> 1, half = rem & 1;
        short8v v = *reinterpret_cast<const short8v*>(
            qkv + ((size_t)(bt * V_ + row)) * 384 + mat * 128 + h * DH_ + half * 8);
        float* dst = (mat == 0 ? q_lds[row] : (mat == 1 ? k_lds[row] : v_lds[row])) + half * 8;
        #pragma unroll
        for (int u = 0; u < 8; ++u) dst[u] = bf2f(v[u]);
    }
    __syncthreads();
    if (tid < V_ * V_) {
        int i = tid / V_, j = tid - i * V_;
        float acc = 0.f;
        #pragma unroll
        for (int c = 0; c < 4; ++c) {
            float4 qv = *reinterpret_cast<const float4*>(&q_lds[i][4 * c]);
            float4 kv = *reinterpret_cast<const float4*>(&k_lds[j][4 * c]);
            acc += qv.x * kv.x + qv.y * kv.y + qv.z * kv.z + qv.w * kv.w;
        }
        sm[i][j] = acc * 0.25f + bias[((size_t)(bt * V_ + i) * V_ + j) * H_ + h];
    }
    __syncthreads();
    if (tid < V_) {
        float m = -1e30f;
        for (int j = 0; j < V_; ++j) m = fmaxf(m, sm[tid][j]);
        float sum = 0.f;
        for (int j = 0; j < V_; ++j) { float e = __expf(sm[tid][j] - m); sm[tid][j] = e; sum += e; }
        float inv = 1.f / sum;
        for (int j = 0; j < V_; ++j) sm[tid][j] *= inv;
    }
    __syncthreads();
    if (tid < V_ * DH_) {
        int i = tid / DH_, d = tid - i * DH_;
        float o = 0.f;
        #pragma unroll 4
        for (int j = 0; j < V_; ++j) o += sm[i][j] * v_lds[j][d];
        out[((size_t)(bt * V_ + i)) * D_ + h * DH_ + d] = __float2bfloat16(o);
    }
}

// ---------------------------------------------------------------------------
// Temporal attention: per (b, h). bf16 qkv staged to f32 LDS; softmax in regs.
// Lane jt owns j = 4*jj + jt (strided): conflict-free k reads.
__global__ __launch_bounds__(256) void attn_temporal_kernel(
        const __hip_bfloat16* __restrict__ qkv, __hip_bfloat16* __restrict__ out) {
    int b = blockIdx.x;
    int h = blockIdx.y;
    __shared__ float q_lds[T_][20];
    __shared__ float k_lds[T_][20];
    __shared__ float v_lds[T_][20];
    __shared__ float sm[T_][68];
    int tid = threadIdx.x;
    // stage: 62 rows x 2 halves x 3 matrices = 372 chunks of 8 bf16 (16B loads)
    for (int idx = tid; idx < T_ * 2 * 3; idx += 256) {
        int mat = idx / (T_ * 2);
        int rem = idx - mat * (T_ * 2);
        int row = rem >> 1, half = rem & 1;
        short8v v = *reinterpret_cast<const short8v*>(
            qkv + ((size_t)(b * T_ + row)) * 384 + mat * 128 + h * DH_ + half * 8);
        float* dst = (mat == 0 ? q_lds[row] : (mat == 1 ? k_lds[row] : v_lds[row])) + half * 8;
        #pragma unroll
        for (int u = 0; u < 8; ++u) dst[u] = bf2f(v[u]);
    }
    __syncthreads();
    if (tid < T_ * 4) {
        int i = tid >> 2, jt = tid & 3;
        float qreg[16];
        #pragma unroll
        for (int c = 0; c < 4; ++c) {
            float4 qv = *reinterpret_cast<const float4*>(&q_lds[i][4 * c]);
            qreg[4 * c + 0] = qv.x * 0.25f;
            qreg[4 * c + 1] = qv.y * 0.25f;
            qreg[4 * c + 2] = qv.z * 0.25f;
            qreg[4 * c + 3] = qv.w * 0.25f;
        }
        float s[16];
        #pragma unroll
        for (int jj = 0; jj < 16; ++jj) {
            int j = jj * 4 + jt;
            float acc = -1e30f;
            if (j < T_) {
                acc = 0.f;
                const float* kr = k_lds[j];
                #pragma unroll
                for (int c = 0; c < 4; ++c) {
                    float4 kv = *reinterpret_cast<const float4*>(&kr[4 * c]);
                    acc += qreg[4*c+0] * kv.x + qreg[4*c+1] * kv.y
                         + qreg[4*c+2] * kv.z + qreg[4*c+3] * kv.w;
                }
            }
            s[jj] = acc;
        }
        float m = -1e30f;
        #pragma unroll
        for (int jj = 0; jj < 16; ++jj) m = fmaxf(m, s[jj]);
        m = fmaxf(m, __shfl_xor(m, 1, 64));
        m = fmaxf(m, __shfl_xor(m, 2, 64));
        float sum = 0.f;
        #pragma unroll
        for (int jj = 0; jj < 16; ++jj) {
            int j = jj * 4 + jt;
            float e = (j < T_) ? __expf(s[jj] - m) : 0.f;
            s[jj] = e;
            sum += e;
        }
        sum += __shfl_xor(sum, 1, 64);
        sum += __shfl_xor(sum, 2, 64);
        float inv = 1.f / sum;
        #pragma unroll
        for (int jj = 0; jj < 16; ++jj) {
            int j = jj * 4 + jt;
            if (j < T_) sm[i][j] = s[jj] * inv;
        }
    }
    __syncthreads();
    if (tid < T_ * 4) {
        int i = tid >> 2, dg = tid & 3;
        float4 o = {0.f, 0.f, 0.f, 0.f};
        for (int j = 0; j < T_; ++j) {
            float pp = sm[i][j];
            const float4 vv = *reinterpret_cast<const float4*>(&v_lds[j][4 * dg]);
            o.x += pp * vv.x; o.y += pp * vv.y; o.z += pp * vv.z; o.w += pp * vv.w;
        }
        bf4 ov = { __float2bfloat16(o.x), __float2bfloat16(o.y),
                   __float2bfloat16(o.z), __float2bfloat16(o.w) };
        *reinterpret_cast<bf4*>(out + ((size_t)(b * T_ + i)) * D_ + h * DH_ + 4 * dg) = ov;
    }
}

// ---------------------------------------------------------------------------
// out = LN(x + r) * g + b; optionally fp32 and/or bf16 outputs.
template<bool O32, bool O16>
__global__ __launch_bounds__(64) void ln_add_kernel(
        const float* __restrict__ x, const float* __restrict__ r,
        const float* __restrict__ g, const float* __restrict__ b,
        float* __restrict__ o32, __hip_bfloat16* __restrict__ o16) {
    int row = blockIdx.x;
    int lane = threadIdx.x;
    const float* xr = x + (size_t)row * D_;
    const float* rr = r + (size_t)row * D_;
    float v0 = xr[lane] + rr[lane];
    float v1 = xr[lane + 64] + rr[lane + 64];
    float s = v0 + v1, sq = v0 * v0 + v1 * v1;
    #pragma unroll
    for (int off = 32; off > 0; off >>= 1) {
        s += __shfl_xor(s, off, 64);
        sq += __shfl_xor(sq, off, 64);
    }
    float mean = s * (1.f / 128.f);
    float var = sq * (1.f / 128.f) - mean * mean;
    float rstd = rsqrtf(var + 1e-5f);
    float a0 = (v0 - mean) * rstd * g[lane]      + b[lane];
    float a1 = (v1 - mean) * rstd * g[lane + 64] + b[lane + 64];
    if (O32) {
        float* o = o32 + (size_t)row * D_;
        o[lane] = a0; o[lane + 64] = a1;
    }
    if (O16) {
        __hip_bfloat16* o = o16 + (size_t)row * D_;
        o[lane] = __float2bfloat16(a0); o[lane + 64] = __float2bfloat16(a1);
    }
}

// y += LN(x + r)*g + b; y_bf = bf16(y)   (fused temporal tail)
__global__ __launch_bounds__(64) void ln_add_add_kernel(
        const float* __restrict__ x, const float* __restrict__ r,
        const float* __restrict__ g, const float* __restrict__ b,
        float* __restrict__ y, __hip_bfloat16* __restrict__ y_bf) {
    int row = blockIdx.x;
    int lane = threadIdx.x;
    const float* xr = x + (size_t)row * D_;
    const float* rr = r + (size_t)row * D_;
    float v0 = xr[lane] + rr[lane];
    float v1 = xr[lane + 64] + rr[lane + 64];
    float s = v0 + v1, sq = v0 * v0 + v1 * v1;
    #pragma unroll
    for (int off = 32; off > 0; off >>= 1) {
        s += __shfl_xor(s, off, 64);
        sq += __shfl_xor(sq, off, 64);
    }
    float mean = s * (1.f / 128.f);
    float var = sq * (1.f / 128.f) - mean * mean;
    float rstd = rsqrtf(var + 1e-5f);
    float a0 = (v0 - mean) * rstd * g[lane]      + b[lane];
    float a1 = (v1 - mean) * rstd * g[lane + 64] + b[lane + 64];
    float* yp = y + (size_t)row * D_;
    __hip_bfloat16* yb = y_bf + (size_t)row * D_;
    float y0 = yp[lane] + a0;
    float y1v = yp[lane + 64] + a1;
    yp[lane] = y0;       yb[lane] = __float2bfloat16(y0);
    yp[lane + 64] = y1v; yb[lane + 64] = __float2bfloat16(y1v);
}

// ---------------------------------------------------------------------------
extern "C" void kernel_launch(void* const* d_in, const int* in_sizes, int n_in,
                              void* d_out, int out_size, void* d_ws, size_t ws_size,
                              hipStream_t stream) {
    const float* pose    = (const float*)d_in[0];
    const float* W_pose  = (const float*)d_in[1];
    const float* W_emb   = (const float*)d_in[2];
    const float* prelu_a = (const float*)d_in[3];
    const float* W_bias  = (const float*)d_in[4];
    const float* gWqkv   = (const float*)d_in[5];
    const float* gbqkv   = (const float*)d_in[6];
    const float* gWo     = (const float*)d_in[7];
    const float* gbo     = (const float*)d_in[8];
    const float* gln1g   = (const float*)d_in[9];
    const float* gln1b   = (const float*)d_in[10];
    const float* gW1     = (const float*)d_in[11];
    const float* gb1     = (const float*)d_in[12];
    const float* gW2     = (const float*)d_in[13];
    const float* gb2     = (const float*)d_in[14];
    const float* gln2g   = (const float*)d_in[15];
    const float* gln2b   = (const float*)d_in[16];
    const float* deW     = (const float*)d_in[17];
    const float* deb     = (const float*)d_in[18];
    const float* tWqkv   = (const float*)d_in[19];
    const float* tbqkv   = (const float*)d_in[20];
    const float* tWo     = (const float*)d_in[21];
    const float* tbo     = (const float*)d_in[22];
    const float* tln1g   = (const float*)d_in[23];
    const float* tln1b   = (const float*)d_in[24];
    const float* tW1     = (const float*)d_in[25];
    const float* tb1     = (const float*)d_in[26];
    const float* tW2     = (const float*)d_in[27];
    const float* tb2     = (const float*)d_in[28];
    const float* tln2g   = (const float*)d_in[29];
    const float* tln2b   = (const float*)d_in[30];
    const float* W_out   = (const float*)d_in[31];

    float* ws = (float*)d_ws;
    // workspace layout (float-slot offsets)
    __hip_bfloat16* p_bf   = (__hip_bfloat16*)(ws + 0);          // ROWS*32 bf16
    float*          y      = ws + 301568;                        // ROWS*128 f32
    __hip_bfloat16* y_bf   = (__hip_bfloat16*)(ws + 2714112);    // ROWS*128 bf16
    float*          biasbuf= ws + 3920384;                       // BT*361*8 f32
    float*          big    = ws + 6785280;                       // 7,237,632 f32
    __hip_bfloat16* qkv_bf = (__hip_bfloat16*)big;               // ROWS*384 bf16
    float*          tmp    = big;                                // ROWS*128 f32 (post-attn)
    __hip_bfloat16* hid_bf = (__hip_bfloat16*)(big + 2412544);   // ROWS*256 bf16
    float*          y1     = big + 4825088;                      // ROWS*128 f32
    __hip_bfloat16* attn_bf= (__hip_bfloat16*)(ws + 14022912);   // ROWS*128 bf16
    float*          t2     = ws + 15229184;                      // ROWS*128 f32 region
    __hip_bfloat16* y1_bf  = (__hip_bfloat16*)t2;                // (phase-disjoint with t2)
    __hip_bfloat16* t2_bf  = (__hip_bfloat16*)t2;
    __hip_bfloat16* w_bf   = (__hip_bfloat16*)(ws + 17641728);   // 585,728 bf16 weights
    float*          w2     = ws + 17934592;                      // 512 f32 (Wbias@Wemb, 2 layers)
    float*          outf   = (float*)d_out;

    // bf16 weight offsets (elems)
    const int oWpose = 0, oWemb = 4096, oGqkv = 20480, oGwo = 118784, oGw1 = 151552,
              oGw2 = 217088, oDe = 282624, oTqkv = 315392, oTwo = 413696,
              oTw1 = 446464, oTw2 = 512000, oWout = 577536;

    const int GX = (ROWS + 63) / 64;   // 295 row-pair tiles

    wconv_kernel<<<(585728 + 255) / 256, 256, 0, stream>>>(
        W_pose, W_emb, gWqkv, gWo, gW1, gW2, deW, tWqkv, tWo, tW1, tW2, W_out, w_bf);
    w2_kernel<<<1, 512, 0, stream>>>(W_bias, W_emb, w2);
    transpose_kernel<<<(B_*T_*V_*C_ + 255) / 256, 256, 0, stream>>>(pose, p_bf);
    // y = p @ W_pose^T
    mfma_linear<128, 32, 0, false, true, true><<<dim3(GX, 1), 256, 0, stream>>>(
        p_bf, w_bf + oWpose, nullptr, y, y_bf);

    for (int i = 0; i < 2; ++i) {
        // ---- graph encoder ----
        bias2_kernel<<<BT_, 256, 0, stream>>>(
            p_bf, w_bf + oWemb + i * 8192, prelu_a + i,
            W_bias + (size_t)i * H_ * HD_, w2 + i * 256, biasbuf);
        mfma_linear<384, 128, 0, true, false, true><<<dim3(GX, 3), 256, 0, stream>>>(
            y_bf, w_bf + oGqkv + i * 49152, gbqkv + (size_t)i * 384, nullptr, qkv_bf);
        attn_graph_kernel<<<dim3(BT_, H_), 384, 0, stream>>>(qkv_bf, biasbuf, attn_bf);
        mfma_linear<128, 128, 0, true, true, false><<<dim3(GX, 1), 256, 0, stream>>>(
            attn_bf, w_bf + oGwo + i * 16384, gbo + (size_t)i * D_, tmp, nullptr);
        ln_add_kernel<true, true><<<ROWS, 64, 0, stream>>>(
            y, tmp, gln1g + (size_t)i * D_, gln1b + (size_t)i * D_, y1, y1_bf);
        mfma_linear<256, 128, 1, true, false, true><<<dim3(GX, 2), 256, 0, stream>>>(
            y1_bf, w_bf + oGw1 + i * 32768, gb1 + (size_t)i * HD_, nullptr, hid_bf);
        mfma_linear<128, 256, 0, true, true, false><<<dim3(GX, 1), 256, 0, stream>>>(
            hid_bf, w_bf + oGw2 + i * 32768, gb2 + (size_t)i * D_, tmp, nullptr);
        ln_add_kernel<false, true><<<ROWS, 64, 0, stream>>>(
            y1, tmp, gln2g + (size_t)i * D_, gln2b + (size_t)i * D_, nullptr, t2_bf);
        // y = de@t2 + deb + PE   (fused positional-encoding epilogue)
        mfma_linear<128, 128, 3, true, true, true><<<dim3(GX, 1), 256, 0, stream>>>(
            t2_bf, w_bf + oDe + i * 16384, deb + (size_t)i * D_, y, y_bf);

        // ---- temporal encoder ----
        mfma_linear<384, 128, 0, true, false, true><<<dim3(GX, 3), 256, 0, stream>>>(
            y_bf, w_bf + oTqkv + i * 49152, tbqkv + (size_t)i * 384, nullptr, qkv_bf);
        attn_temporal_kernel<<<dim3(BV_, H_), 256, 0, stream>>>(qkv_bf, attn_bf);
        mfma_linear<128, 128, 0, true, true, false><<<dim3(GX, 1), 256, 0, stream>>>(
            attn_bf, w_bf + oTwo + i * 16384, tbo + (size_t)i * D_, tmp, nullptr);
        ln_add_kernel<true, true><<<ROWS, 64, 0, stream>>>(
            y, tmp, tln1g + (size_t)i * D_, tln1b + (size_t)i * D_, y1, y1_bf);
        mfma_linear<256, 128, 1, true, false, true><<<dim3(GX, 2), 256, 0, stream>>>(
            y1_bf, w_bf + oTw1 + i * 32768, tb1 + (size_t)i * HD_, nullptr, hid_bf);
        mfma_linear<128, 256, 0, true, true, false><<<dim3(GX, 1), 256, 0, stream>>>(
            hid_bf, w_bf + oTw2 + i * 32768, tb2 + (size_t)i * D_, tmp, nullptr);
        // y += LN(y1 + tmp)  (fused ln_add + add)
        ln_add_add_kernel<<<ROWS, 64, 0, stream>>>(
            y1, tmp, tln2g + (size_t)i * D_, tln2b + (size_t)i * D_, y, y_bf);
    }

    // final projection + LeakyReLU
    mfma_linear<64, 128, 2, false, true, false><<<dim3(GX, 1), 256, 0, stream>>>(
        y_bf, w_bf + oWout, nullptr, outf, nullptr);
}

// Round 15
// 598.911 us; speedup vs baseline: 1.3138x; 1.0466x over previous
//
#include <hip/hip_runtime.h>
#include <hip/hip_bf16.h>
#include <math.h>

// Shapes (fixed by the problem)
#define B_  16
#define C_  32
#define T_  62
#define V_  19
#define D_  128
#define HD_ 256
#define H_  8
#define DH_ 16            // D_/H_
#define ROWS 18848        // B*T*V == B*V*T  (= 32*589)
#define BT_ 992           // B*T
#define BV_ 304           // B*V

typedef __attribute__((ext_vector_type(8))) short short8v;   // 8 bf16 (4 VGPRs)
typedef __attribute__((ext_vector_type(4))) float f32x4;
typedef __attribute__((ext_vector_type(16))) float f32x16;

struct alignas(8) bf4 { __hip_bfloat16 x, y, z, w; };

__device__ __forceinline__ float bf2f(short s) {
    return __uint_as_float(((unsigned)(unsigned short)s) << 16);
}

// ---------------------------------------------------------------------------
// pose [B,C,T,V] -> p_bf [B,T,V,C] (bf16; only consumed by bf16 GEMMs)
__global__ void transpose_kernel(const float* __restrict__ pose, __hip_bfloat16* __restrict__ p_bf) {
    int idx = blockIdx.x * 256 + threadIdx.x;
    if (idx >= B_ * T_ * V_ * C_) return;
    int c = idx & 31;
    int rest = idx >> 5;          // b*T*V + t*V + v
    int v = rest % V_;
    int rest2 = rest / V_;
    int t = rest2 % T_;
    int b = rest2 / T_;
    p_bf[idx] = __float2bfloat16(pose[((size_t)((b * C_ + c) * T_ + t)) * V_ + v]);
}

// ---------------------------------------------------------------------------
// Convert all weight matrices to bf16 into one contiguous buffer (one launch).
__global__ void wconv_kernel(
        const float* s0, const float* s1, const float* s2, const float* s3,
        const float* s4, const float* s5, const float* s6, const float* s7,
        const float* s8, const float* s9, const float* s10, const float* s11,
        __hip_bfloat16* __restrict__ dst) {
    int idx = blockIdx.x * 256 + threadIdx.x;
    if (idx >= 585728) return;
    const float* s; int base;
    if      (idx <   4096) { s = s0;  base = 0;      }
    else if (idx <  20480) { s = s1;  base = 4096;   }
    else if (idx < 118784) { s = s2;  base = 20480;  }
    else if (idx < 151552) { s = s3;  base = 118784; }
    else if (idx < 217088) { s = s4;  base = 151552; }
    else if (idx < 282624) { s = s5;  base = 217088; }
    else if (idx < 315392) { s = s6;  base = 282624; }
    else if (idx < 413696) { s = s7;  base = 315392; }
    else if (idx < 446464) { s = s8;  base = 413696; }
    else if (idx < 512000) { s = s9;  base = 446464; }
    else if (idx < 577536) { s = s10; base = 512000; }
    else                   { s = s11; base = 577536; }
    dst[idx] = __float2bfloat16(s[idx - base]);
}

// ---------------------------------------------------------------------------
// W2[layer][g][c] = sum_hh Wbias[layer,g,hh] * Wemb[layer,hh,c]   (8x32 per layer)
__global__ __launch_bounds__(512) void w2_kernel(
        const float* __restrict__ Wbias, const float* __restrict__ Wemb,
        float* __restrict__ w2) {
    int tid = threadIdx.x;
    int layer = tid >> 8, g = (tid >> 5) & 7, c = tid & 31;
    float acc = 0.f;
    for (int hh = 0; hh < HD_; ++hh)
        acc += Wbias[layer * 2048 + g * HD_ + hh] * Wemb[layer * 8192 + hh * C_ + c];
    w2[layer * 256 + g * C_ + c] = acc;
}

// ---------------------------------------------------------------------------
// MFMA linear, 32x32 tiles, 2 ROW-TILES PER WAVE (B-fragment reuse).
// mfma_f32_32x32x16_bf16: A/B lane->(row=l&31, k=(l>>5)*8+j);
// C/D: col=l&31, row=(reg&3)+8*(reg>>2)+4*(l>>5)  [guide §3, m74/m101 verified]
// grid = ((ROWS+63)/64, ceil(N/128)); wave w -> n-tile blockIdx.y*4+w.
// EPI: 0 none, 1 relu, 2 leaky(0.01), 3 add positional encoding
template<int N, int K, int EPI, bool HASBIAS, bool O32, bool O16>
__global__ __launch_bounds__(256) void mfma_linear(
        const __hip_bfloat16* __restrict__ A, const __hip_bfloat16* __restrict__ W,
        const float* __restrict__ bias, float* __restrict__ out32,
        __hip_bfloat16* __restrict__ out16) {
    int wave = threadIdx.x >> 6;
    int lane = threadIdx.x & 63;
    int nt = blockIdx.y * 4 + wave;
    int n0 = nt * 32;
    if (n0 >= N) return;
    int r0 = blockIdx.x * 64;
    int r1 = r0 + 32;
    bool has2 = (r1 < ROWS);
    int rl = lane & 31;
    int kk = (lane >> 5) * 8;     // 0 or 8
    const short* Ab0 = (const short*)A + (size_t)(r0 + rl) * K + kk;
    const short* Ab1 = (const short*)A + (size_t)(r1 + rl) * K + kk;
    const short* Wb  = (const short*)W + (size_t)(n0 + rl) * K + kk;
    f32x16 acc0 = {0.f,0.f,0.f,0.f,0.f,0.f,0.f,0.f,0.f,0.f,0.f,0.f,0.f,0.f,0.f,0.f};
    f32x16 acc1 = acc0;
    #pragma unroll
    for (int kb = 0; kb < K / 16; ++kb) {
        short8v b  = *reinterpret_cast<const short8v*>(Wb  + kb * 16);
        short8v a0 = *reinterpret_cast<const short8v*>(Ab0 + kb * 16);
        acc0 = __builtin_amdgcn_mfma_f32_32x32x16_bf16(a0, b, acc0, 0, 0, 0);
        if (has2) {
            short8v a1 = *reinterpret_cast<const short8v*>(Ab1 + kb * 16);
            acc1 = __builtin_amdgcn_mfma_f32_32x32x16_bf16(a1, b, acc1, 0, 0, 0);
        }
    }
    int oc = n0 + rl;
    float bv = HASBIAS ? bias[oc] : 0.f;
    float freq = 0.f;
    if (EPI == 3) freq = expf(-(float)(oc & ~1) * (9.210340371976184f / 128.f));
    #pragma unroll
    for (int t2 = 0; t2 < 2; ++t2) {
        if (t2 == 1 && !has2) break;
        int rb = t2 ? r1 : r0;
        f32x16 acc = t2 ? acc1 : acc0;
        #pragma unroll
        for (int reg = 0; reg < 16; ++reg) {
            int orow = rb + (reg & 3) + 8 * (reg >> 2) + 4 * (lane >> 5);
            float v = acc[reg] + bv;
            if (EPI == 1) v = fmaxf(v, 0.f);
            if (EPI == 2) v = v >= 0.f ? v : 0.01f * v;
            if (EPI == 3) {
                int t = orow % T_;
                float ang = (float)t * freq;
                v += (oc & 1) ? cosf(ang) : sinf(ang);
            }
            if (O32) out32[(size_t)orow * N + oc] = v;
            if (O16) out16[(size_t)orow * N + oc] = __float2bfloat16(v);
        }
    }
}

// ---------------------------------------------------------------------------
// Fused FFN: out[r,:] = W2 @ relu(W1 @ A[r,:] + b1) + b2.
// One block per 32-row strip (grid ROWS/32). Phase 1: hid (32x256) -> LDS bf16;
// phase 2: out (32x128) with A-fragments from LDS (pad 264 -> <=4-way conflicts).
__global__ __launch_bounds__(256) void ffn_kernel(
        const __hip_bfloat16* __restrict__ A, const __hip_bfloat16* __restrict__ W1,
        const float* __restrict__ b1, const __hip_bfloat16* __restrict__ W2,
        const float* __restrict__ b2, float* __restrict__ out) {
    __shared__ __hip_bfloat16 hid[32][264];
    int wave = threadIdx.x >> 6;
    int lane = threadIdx.x & 63;
    int r0 = blockIdx.x * 32;
    int rl = lane & 31;
    int kk = (lane >> 5) * 8;     // 0 or 8
    // hoist A-fragments (K=128 -> 8 k-blocks)
    const short* Ab = (const short*)A + (size_t)(r0 + rl) * D_ + kk;
    short8v afr[8];
    #pragma unroll
    for (int kb = 0; kb < 8; ++kb)
        afr[kb] = *reinterpret_cast<const short8v*>(Ab + kb * 16);
    // phase 1: hid columns [wave*32) and [(wave+4)*32)
    #pragma unroll
    for (int pass = 0; pass < 2; ++pass) {
        int n0 = (wave + pass * 4) * 32;
        const short* Wb = (const short*)W1 + (size_t)(n0 + rl) * D_ + kk;
        f32x16 acc = {0.f,0.f,0.f,0.f,0.f,0.f,0.f,0.f,0.f,0.f,0.f,0.f,0.f,0.f,0.f,0.f};
        #pragma unroll
        for (int kb = 0; kb < 8; ++kb) {
            short8v b = *reinterpret_cast<const short8v*>(Wb + kb * 16);
            acc = __builtin_amdgcn_mfma_f32_32x32x16_bf16(afr[kb], b, acc, 0, 0, 0);
        }
        int oc = n0 + rl;
        float bv = b1[oc];
        #pragma unroll
        for (int reg = 0; reg < 16; ++reg) {
            int orow = (reg & 3) + 8 * (reg >> 2) + 4 * (lane >> 5);
            hid[orow][oc] = __float2bfloat16(fmaxf(acc[reg] + bv, 0.f));
        }
    }
    __syncthreads();
    // phase 2: out n-tile = wave (N=128 -> 4 tiles), K=256 from LDS
    {
        int n0 = wave * 32;
        const short* Wb = (const short*)W2 + (size_t)(n0 + rl) * HD_ + kk;
        const short* Hrow = (const short*)&hid[rl][0];
        f32x16 acc = {0.f,0.f,0.f,0.f,0.f,0.f,0.f,0.f,0.f,0.f,0.f,0.f,0.f,0.f,0.f,0.f};
        #pragma unroll
        for (int kb = 0; kb < 16; ++kb) {
            short8v a = *reinterpret_cast<const short8v*>(Hrow + kb * 16 + kk);
            short8v b = *reinterpret_cast<const short8v*>(Wb + kb * 16);
            acc = __builtin_amdgcn_mfma_f32_32x32x16_bf16(a, b, acc, 0, 0, 0);
        }
        int oc = n0 + rl;
        float bv = b2[oc];
        #pragma unroll
        for (int reg = 0; reg < 16; ++reg) {
            int orow = r0 + (reg & 3) + 8 * (reg >> 2) + 4 * (lane >> 5);
            out[(size_t)orow * D_ + oc] = acc[reg] + bv;
        }
    }
}

// ---------------------------------------------------------------------------
// bias2 v4: e computed IN-BLOCK (e = p@Wemb^T only feeds this kernel).
// prelu(x) = cL*x + cA*|x|; linear term telescopes via f = p@W2^T (W2=Wbias@Wemb);
// |d| term symmetric -> 190 upper-tri pairs. es stride 257 (conflict-free scalar).
__global__ __launch_bounds__(256) void bias2_kernel(
        const __hip_bfloat16* __restrict__ p_bf, const __hip_bfloat16* __restrict__ wemb_bf,
        const float* __restrict__ prelu_a, const float* __restrict__ Wbias,
        const float* __restrict__ w2, float* __restrict__ bias) {
    int bt = blockIdx.x;
    __shared__ float es[V_ * 257];
    __shared__ float ps[V_ * 33];
    __shared__ float f_lds[V_ * 8];
    int tid = threadIdx.x;
    // stage p (19x32 bf16 -> f32)
    if (tid < V_ * 8) {
        int v = tid >> 3, c4 = (tid & 7) * 4;
        bf4 pv = *reinterpret_cast<const bf4*>(&p_bf[((size_t)(bt * V_ + v)) * C_ + c4]);
        float* d = &ps[v * 33 + c4];
        d[0] = __bfloat162float(pv.x); d[1] = __bfloat162float(pv.y);
        d[2] = __bfloat162float(pv.z); d[3] = __bfloat162float(pv.w);
    }
    __syncthreads();
    // compute e rows: thread tid owns embedding dim hh=tid for all 19 vertices
    {
        float wr[C_];
        const __hip_bfloat16* wrow = wemb_bf + (size_t)tid * C_;
        #pragma unroll
        for (int c4 = 0; c4 < 8; ++c4) {
            bf4 wv = *reinterpret_cast<const bf4*>(wrow + c4 * 4);
            wr[c4 * 4 + 0] = __bfloat162float(wv.x);
            wr[c4 * 4 + 1] = __bfloat162float(wv.y);
            wr[c4 * 4 + 2] = __bfloat162float(wv.z);
            wr[c4 * 4 + 3] = __bfloat162float(wv.w);
        }
        for (int v = 0; v < V_; ++v) {
            const float* pr = &ps[v * 33];
            float acc = 0.f;
            #pragma unroll
            for (int c = 0; c < C_; ++c) acc += pr[c] * wr[c];
            es[v * 257 + tid] = acc;
        }
    }
    // f[v,g] = ps[v,:] . w2[g,:]  (K=32)
    if (tid < V_ * 8) {
        int v = tid >> 3, g = tid & 7;
        const float* pr = &ps[v * 33];
        const float* wr = &w2[g * C_];
        float acc = 0.f;
        #pragma unroll
        for (int c = 0; c < C_; ++c) acc += pr[c] * wr[c];
        f_lds[v * 8 + g] = acc;
    }
    __syncthreads();
    // phase 2: 190 upper-tri pairs
    if (tid < 190) {
        int i = 0, rem = tid, cnt = V_;
        while (rem >= cnt) { rem -= cnt; ++i; --cnt; }
        int j = i + rem;                       // i <= j
        const float a = prelu_a[0];
        const float scale = 0.35355339059327373f;   // 1/sqrt(8)
        const float cL = 0.5f * (1.f + a) * scale;
        const float cA = 0.5f * (1.f - a) * scale;
        const float* ei = es + i * 257;
        const float* ej = es + j * 257;
        float S[H_] = {0.f, 0.f, 0.f, 0.f, 0.f, 0.f, 0.f, 0.f};
        #pragma unroll 4
        for (int hh = 0; hh < HD_; ++hh) {
            float d = ej[hh] - ei[hh];
            float ad = fabsf(d);
            const float* w = Wbias + hh;       // block-uniform -> s_load
            #pragma unroll
            for (int g = 0; g < H_; ++g) S[g] += w[g * HD_] * ad;
        }
        float* bij = bias + ((size_t)bt * (V_ * V_) + i * V_ + j) * H_;
        float* bji = bias + ((size_t)bt * (V_ * V_) + j * V_ + i) * H_;
        #pragma unroll
        for (int g = 0; g < H_; ++g) {
            float lin = cL * (f_lds[j * 8 + g] - f_lds[i * 8 + g]);
            float sym = cA * S[g];
            bij[g] = lin + sym;
            bji[g] = sym - lin;
        }
    }
}

// ---------------------------------------------------------------------------
// Graph attention: per (bt, h). bf16 qkv staged to f32 LDS. bf16 out.
__global__ __launch_bounds__(384) void attn_graph_kernel(
        const __hip_bfloat16* __restrict__ qkv, const float* __restrict__ bias,
        __hip_bfloat16* __restrict__ out) {
    int bt = blockIdx.x;
    int h = blockIdx.y;
    __shared__ float q_lds[V_][20];
    __shared__ float k_lds[V_][20];
    __shared__ float v_lds[V_][20];
    __shared__ float sm[V_][20];
    int tid = threadIdx.x;
    // stage: 19 rows x 2 halves x 3 matrices = 114 chunks of 8 bf16 (16B loads)
    for (int idx = tid; idx < V_ * 2 * 3; idx += 384) {
        int mat = idx / (V_ * 2);
        int rem = idx - mat * (V_ * 2);
        int row = rem >> 1, half = rem & 1;
        short8v v = *reinterpret_cast<const short8v*>(
            qkv + ((size_t)(bt * V_ + row)) * 384 + mat * 128 + h * DH_ + half * 8);
        float* dst = (mat == 0 ? q_lds[row] : (mat == 1 ? k_lds[row] : v_lds[row])) + half * 8;
        #pragma unroll
        for (int u = 0; u < 8; ++u) dst[u] = bf2f(v[u]);
    }
    __syncthreads();
    if (tid < V_ * V_) {
        int i = tid / V_, j = tid - i * V_;
        float acc = 0.f;
        #pragma unroll
        for (int c = 0; c < 4; ++c) {
            float4 qv = *reinterpret_cast<const float4*>(&q_lds[i][4 * c]);
            float4 kv = *reinterpret_cast<const float4*>(&k_lds[j][4 * c]);
            acc += qv.x * kv.x + qv.y * kv.y + qv.z * kv.z + qv.w * kv.w;
        }
        sm[i][j] = acc * 0.25f + bias[((size_t)(bt * V_ + i) * V_ + j) * H_ + h];
    }
    __syncthreads();
    if (tid < V_) {
        float m = -1e30f;
        for (int j = 0; j < V_; ++j) m = fmaxf(m, sm[tid][j]);
        float sum = 0.f;
        for (int j = 0; j < V_; ++j) { float e = __expf(sm[tid][j] - m); sm[tid][j] = e; sum += e; }
        float inv = 1.f / sum;
        for (int j = 0; j < V_; ++j) sm[tid][j] *= inv;
    }
    __syncthreads();
    if (tid < V_ * DH_) {
        int i = tid / DH_, d = tid - i * DH_;
        float o = 0.f;
        #pragma unroll 4
        for (int j = 0; j < V_; ++j) o += sm[i][j] * v_lds[j][d];
        out[((size_t)(bt * V_ + i)) * D_ + h * DH_ + d] = __float2bfloat16(o);
    }
}

// ---------------------------------------------------------------------------
// Temporal attention: per (b, h). bf16 qkv staged to f32 LDS; softmax in regs.
// Lane jt owns j = 4*jj + jt (strided): conflict-free k reads.
__global__ __launch_bounds__(256) void attn_temporal_kernel(
        const __hip_bfloat16* __restrict__ qkv, __hip_bfloat16* __restrict__ out) {
    int b = blockIdx.x;
    int h = blockIdx.y;
    __shared__ float q_lds[T_][20];
    __shared__ float k_lds[T_][20];
    __shared__ float v_lds[T_][20];
    __shared__ float sm[T_][68];
    int tid = threadIdx.x;
    // stage: 62 rows x 2 halves x 3 matrices = 372 chunks of 8 bf16 (16B loads)
    for (int idx = tid; idx < T_ * 2 * 3; idx += 256) {
        int mat = idx / (T_ * 2);
        int rem = idx - mat * (T_ * 2);
        int row = rem >> 1, half = rem & 1;
        short8v v = *reinterpret_cast<const short8v*>(
            qkv + ((size_t)(b * T_ + row)) * 384 + mat * 128 + h * DH_ + half * 8);
        float* dst = (mat == 0 ? q_lds[row] : (mat == 1 ? k_lds[row] : v_lds[row])) + half * 8;
        #pragma unroll
        for (int u = 0; u < 8; ++u) dst[u] = bf2f(v[u]);
    }
    __syncthreads();
    if (tid < T_ * 4) {
        int i = tid >> 2, jt = tid & 3;
        float qreg[16];
        #pragma unroll
        for (int c = 0; c < 4; ++c) {
            float4 qv = *reinterpret_cast<const float4*>(&q_lds[i][4 * c]);
            qreg[4 * c + 0] = qv.x * 0.25f;
            qreg[4 * c + 1] = qv.y * 0.25f;
            qreg[4 * c + 2] = qv.z * 0.25f;
            qreg[4 * c + 3] = qv.w * 0.25f;
        }
        float s[16];
        #pragma unroll
        for (int jj = 0; jj < 16; ++jj) {
            int j = jj * 4 + jt;
            float acc = -1e30f;
            if (j < T_) {
                acc = 0.f;
                const float* kr = k_lds[j];
                #pragma unroll
                for (int c = 0; c < 4; ++c) {
                    float4 kv = *reinterpret_cast<const float4*>(&kr[4 * c]);
                    acc += qreg[4*c+0] * kv.x + qreg[4*c+1] * kv.y
                         + qreg[4*c+2] * kv.z + qreg[4*c+3] * kv.w;
                }
            }
            s[jj] = acc;
        }
        float m = -1e30f;
        #pragma unroll
        for (int jj = 0; jj < 16; ++jj) m = fmaxf(m, s[jj]);
        m = fmaxf(m, __shfl_xor(m, 1, 64));
        m = fmaxf(m, __shfl_xor(m, 2, 64));
        float sum = 0.f;
        #pragma unroll
        for (int jj = 0; jj < 16; ++jj) {
            int j = jj * 4 + jt;
            float e = (j < T_) ? __expf(s[jj] - m) : 0.f;
            s[jj] = e;
            sum += e;
        }
        sum += __shfl_xor(sum, 1, 64);
        sum += __shfl_xor(sum, 2, 64);
        float inv = 1.f / sum;
        #pragma unroll
        for (int jj = 0; jj < 16; ++jj) {
            int j = jj * 4 + jt;
            if (j < T_) sm[i][j] = s[jj] * inv;
        }
    }
    __syncthreads();
    if (tid < T_ * 4) {
        int i = tid >> 2, dg = tid & 3;
        float4 o = {0.f, 0.f, 0.f, 0.f};
        for (int j = 0; j < T_; ++j) {
            float pp = sm[i][j];
            const float4 vv = *reinterpret_cast<const float4*>(&v_lds[j][4 * dg]);
            o.x += pp * vv.x; o.y += pp * vv.y; o.z += pp * vv.z; o.w += pp * vv.w;
        }
        bf4 ov = { __float2bfloat16(o.x), __float2bfloat16(o.y),
                   __float2bfloat16(o.z), __float2bfloat16(o.w) };
        *reinterpret_cast<bf4*>(out + ((size_t)(b * T_ + i)) * D_ + h * DH_ + 4 * dg) = ov;
    }
}

// ---------------------------------------------------------------------------
// out = LN(x + r) * g + b; 4 rows/block (wave w -> row blockIdx*4+w).
template<bool O32, bool O16>
__global__ __launch_bounds__(256) void ln_add_kernel(
        const float* __restrict__ x, const float* __restrict__ r,
        const float* __restrict__ g, const float* __restrict__ b,
        float* __restrict__ o32, __hip_bfloat16* __restrict__ o16) {
    int row = blockIdx.x * 4 + (threadIdx.x >> 6);
    int lane = threadIdx.x & 63;
    const float* xr = x + (size_t)row * D_;
    const float* rr = r + (size_t)row * D_;
    float v0 = xr[lane] + rr[lane];
    float v1 = xr[lane + 64] + rr[lane + 64];
    float s = v0 + v1, sq = v0 * v0 + v1 * v1;
    #pragma unroll
    for (int off = 32; off > 0; off >>= 1) {
        s += __shfl_xor(s, off, 64);
        sq += __shfl_xor(sq, off, 64);
    }
    float mean = s * (1.f / 128.f);
    float var = sq * (1.f / 128.f) - mean * mean;
    float rstd = rsqrtf(var + 1e-5f);
    float a0 = (v0 - mean) * rstd * g[lane]      + b[lane];
    float a1 = (v1 - mean) * rstd * g[lane + 64] + b[lane + 64];
    if (O32) {
        float* o = o32 + (size_t)row * D_;
        o[lane] = a0; o[lane + 64] = a1;
    }
    if (O16) {
        __hip_bfloat16* o = o16 + (size_t)row * D_;
        o[lane] = __float2bfloat16(a0); o[lane + 64] = __float2bfloat16(a1);
    }
}

// y += LN(x + r)*g + b; y_bf = bf16(y). 4 rows/block.
__global__ __launch_bounds__(256) void ln_add_add_kernel(
        const float* __restrict__ x, const float* __restrict__ r,
        const float* __restrict__ g, const float* __restrict__ b,
        float* __restrict__ y, __hip_bfloat16* __restrict__ y_bf) {
    int row = blockIdx.x * 4 + (threadIdx.x >> 6);
    int lane = threadIdx.x & 63;
    const float* xr = x + (size_t)row * D_;
    const float* rr = r + (size_t)row * D_;
    float v0 = xr[lane] + rr[lane];
    float v1 = xr[lane + 64] + rr[lane + 64];
    float s = v0 + v1, sq = v0 * v0 + v1 * v1;
    #pragma unroll
    for (int off = 32; off > 0; off >>= 1) {
        s += __shfl_xor(s, off, 64);
        sq += __shfl_xor(sq, off, 64);
    }
    float mean = s * (1.f / 128.f);
    float var = sq * (1.f / 128.f) - mean * mean;
    float rstd = rsqrtf(var + 1e-5f);
    float a0 = (v0 - mean) * rstd * g[lane]      + b[lane];
    float a1 = (v1 - mean) * rstd * g[lane + 64] + b[lane + 64];
    float* yp = y + (size_t)row * D_;
    __hip_bfloat16* yb = y_bf + (size_t)row * D_;
    float y0 = yp[lane] + a0;
    float y1v = yp[lane + 64] + a1;
    yp[lane] = y0;       yb[lane] = __float2bfloat16(y0);
    yp[lane + 64] = y1v; yb[lane + 64] = __float2bfloat16(y1v);
}

// ---------------------------------------------------------------------------
extern "C" void kernel_launch(void* const* d_in, const int* in_sizes, int n_in,
                              void* d_out, int out_size, void* d_ws, size_t ws_size,
                              hipStream_t stream) {
    const float* pose    = (const float*)d_in[0];
    const float* W_pose  = (const float*)d_in[1];
    const float* W_emb   = (const float*)d_in[2];
    const float* prelu_a = (const float*)d_in[3];
    const float* W_bias  = (const float*)d_in[4];
    const float* gWqkv   = (const float*)d_in[5];
    const float* gbqkv   = (const float*)d_in[6];
    const float* gWo     = (const float*)d_in[7];
    const float* gbo     = (const float*)d_in[8];
    const float* gln1g   = (const float*)d_in[9];
    const float* gln1b   = (const float*)d_in[10];
    const float* gW1     = (const float*)d_in[11];
    const float* gb1     = (const float*)d_in[12];
    const float* gW2     = (const float*)d_in[13];
    const float* gb2     = (const float*)d_in[14];
    const float* gln2g   = (const float*)d_in[15];
    const float* gln2b   = (const float*)d_in[16];
    const float* deW     = (const float*)d_in[17];
    const float* deb     = (const float*)d_in[18];
    const float* tWqkv   = (const float*)d_in[19];
    const float* tbqkv   = (const float*)d_in[20];
    const float* tWo     = (const float*)d_in[21];
    const float* tbo     = (const float*)d_in[22];
    const float* tln1g   = (const float*)d_in[23];
    const float* tln1b   = (const float*)d_in[24];
    const float* tW1     = (const float*)d_in[25];
    const float* tb1     = (const float*)d_in[26];
    const float* tW2     = (const float*)d_in[27];
    const float* tb2     = (const float*)d_in[28];
    const float* tln2g   = (const float*)d_in[29];
    const float* tln2b   = (const float*)d_in[30];
    const float* W_out   = (const float*)d_in[31];

    float* ws = (float*)d_ws;
    // workspace layout (float-slot offsets)
    __hip_bfloat16* p_bf   = (__hip_bfloat16*)(ws + 0);          // ROWS*32 bf16
    float*          y      = ws + 301568;                        // ROWS*128 f32
    __hip_bfloat16* y_bf   = (__hip_bfloat16*)(ws + 2714112);    // ROWS*128 bf16
    float*          biasbuf= ws + 3920384;                       // BT*361*8 f32
    float*          big    = ws + 6785280;                       // 7,237,632 f32
    __hip_bfloat16* qkv_bf = (__hip_bfloat16*)big;               // ROWS*384 bf16
    float*          tmp    = big;                                // ROWS*128 f32 (post-attn)
    float*          y1     = big + 4825088;                      // ROWS*128 f32
    __hip_bfloat16* attn_bf= (__hip_bfloat16*)(ws + 14022912);   // ROWS*128 bf16
    float*          t2     = ws + 15229184;                      // ROWS*128 f32 region
    __hip_bfloat16* y1_bf  = (__hip_bfloat16*)t2;                // (phase-disjoint with t2)
    __hip_bfloat16* t2_bf  = (__hip_bfloat16*)t2;
    __hip_bfloat16* w_bf   = (__hip_bfloat16*)(ws + 17641728);   // 585,728 bf16 weights
    float*          w2     = ws + 17934592;                      // 512 f32 (Wbias@Wemb, 2 layers)
    float*          outf   = (float*)d_out;

    // bf16 weight offsets (elems)
    const int oWpose = 0, oWemb = 4096, oGqkv = 20480, oGwo = 118784, oGw1 = 151552,
              oGw2 = 217088, oDe = 282624, oTqkv = 315392, oTwo = 413696,
              oTw1 = 446464, oTw2 = 512000, oWout = 577536;

    const int GX = (ROWS + 63) / 64;   // 295 row-pair tiles
    const int LNG = ROWS / 4;          // 4712 LN blocks

    wconv_kernel<<<(585728 + 255) / 256, 256, 0, stream>>>(
        W_pose, W_emb, gWqkv, gWo, gW1, gW2, deW, tWqkv, tWo, tW1, tW2, W_out, w_bf);
    w2_kernel<<<1, 512, 0, stream>>>(W_bias, W_emb, w2);
    transpose_kernel<<<(B_*T_*V_*C_ + 255) / 256, 256, 0, stream>>>(pose, p_bf);
    // y = p @ W_pose^T
    mfma_linear<128, 32, 0, false, true, true><<<dim3(GX, 1), 256, 0, stream>>>(
        p_bf, w_bf + oWpose, nullptr, y, y_bf);

    for (int i = 0; i < 2; ++i) {
        // ---- graph encoder ----
        bias2_kernel<<<BT_, 256, 0, stream>>>(
            p_bf, w_bf + oWemb + i * 8192, prelu_a + i,
            W_bias + (size_t)i * H_ * HD_, w2 + i * 256, biasbuf);
        mfma_linear<384, 128, 0, true, false, true><<<dim3(GX, 3), 256, 0, stream>>>(
            y_bf, w_bf + oGqkv + i * 49152, gbqkv + (size_t)i * 384, nullptr, qkv_bf);
        attn_graph_kernel<<<dim3(BT_, H_), 384, 0, stream>>>(qkv_bf, biasbuf, attn_bf);
        mfma_linear<128, 128, 0, true, true, false><<<dim3(GX, 1), 256, 0, stream>>>(
            attn_bf, w_bf + oGwo + i * 16384, gbo + (size_t)i * D_, tmp, nullptr);
        ln_add_kernel<true, true><<<LNG, 256, 0, stream>>>(
            y, tmp, gln1g + (size_t)i * D_, gln1b + (size_t)i * D_, y1, y1_bf);
        // fused FFN: tmp = W2 @ relu(W1 @ y1 + b1) + b2
        ffn_kernel<<<ROWS / 32, 256, 0, stream>>>(
            y1_bf, w_bf + oGw1 + i * 32768, gb1 + (size_t)i * HD_,
            w_bf + oGw2 + i * 32768, gb2 + (size_t)i * D_, tmp);
        ln_add_kernel<false, true><<<LNG, 256, 0, stream>>>(
            y1, tmp, gln2g + (size_t)i * D_, gln2b + (size_t)i * D_, nullptr, t2_bf);
        // y = de@t2 + deb + PE   (fused positional-encoding epilogue)
        mfma_linear<128, 128, 3, true, true, true><<<dim3(GX, 1), 256, 0, stream>>>(
            t2_bf, w_bf + oDe + i * 16384, deb + (size_t)i * D_, y, y_bf);

        // ---- temporal encoder ----
        mfma_linear<384, 128, 0, true, false, true><<<dim3(GX, 3), 256, 0, stream>>>(
            y_bf, w_bf + oTqkv + i * 49152, tbqkv + (size_t)i * 384, nullptr, qkv_bf);
        attn_temporal_kernel<<<dim3(BV_, H_), 256, 0, stream>>>(qkv_bf, attn_bf);
        mfma_linear<128, 128, 0, true, true, false><<<dim3(GX, 1), 256, 0, stream>>>(
            attn_bf, w_bf + oTwo + i * 16384, tbo + (size_t)i * D_, tmp, nullptr);
        ln_add_kernel<true, true><<<LNG, 256, 0, stream>>>(
            y, tmp, tln1g + (size_t)i * D_, tln1b + (size_t)i * D_, y1, y1_bf);
        ffn_kernel<<<ROWS / 32, 256, 0, stream>>>(
            y1_bf, w_bf + oTw1 + i * 32768, tb1 + (size_t)i * HD_,
            w_bf + oTw2 + i * 32768, tb2 + (size_t)i * D_, tmp);
        // y += LN(y1 + tmp)  (fused ln_add + add)
        ln_add_add_kernel<<<LNG, 256, 0, stream>>>(
            y1, tmp, tln2g + (size_t)i * D_, tln2b + (size_t)i * D_, y, y_bf);
    }

    // final projection + LeakyReLU
    mfma_linear<64, 128, 2, false, true, false><<<dim3(GX, 1), 256, 0, stream>>>(
        y_bf, w_bf + oWout, nullptr, outf, nullptr);
}